// Round 5
// baseline (223.662 us; speedup 1.0000x reference)
//
#include <hip/hip_runtime.h>
#include <math.h>

#define NEGC -1000000000.0f

using f32x4 = __attribute__((ext_vector_type(4))) float;
using s16x8 = __attribute__((ext_vector_type(8))) short;

__device__ __forceinline__ float softplusf(float v){ return log1pf(expf(v)); }
__device__ __forceinline__ short f2bf(float f){   // RNE f32->bf16
  unsigned u = __float_as_uint(f);
  unsigned r = (u + 0x7fffu + ((u >> 16) & 1u)) >> 16;
  return (short)r;
}

// ---------------- Kernel A: pack W1 (256x128 f32) into bf16 B-fragments ----------------
__global__ __launch_bounds__(256) void k_pack(const float* __restrict__ W1,
                                              short* __restrict__ wpack){
  int gid  = blockIdx.x * 256 + threadIdx.x;   // 0..4095
  int lane = gid & 63;
  int ft   = gid >> 6;                         // 0..63
  int kt   = ft >> 2;
  int dt   = ft & 3;
  const float* src = W1 + (size_t)(kt * 16 + (lane & 15)) * 128 + dt * 32 + (lane >> 4) * 8;
  short o[8];
#pragma unroll
  for (int e = 0; e < 8; ++e) o[e] = f2bf(src[e]);
  *(s16x8*)(wpack + (size_t)gid * 8) = *(const s16x8*)o;
}

// ---------------- Kernel B: segment starts via parallel binary search ----------------
__global__ __launch_bounds__(256) void k_seg(const int* __restrict__ batch,
                                             int* __restrict__ starts, int T, int Bn){
  int t = blockIdx.x * 256 + threadIdx.x;
  if (t > Bn) return;
  if (t == Bn){ starts[Bn] = T; return; }
  int lo = 0, hi = T;
  while (lo < hi){ int mid = (lo + hi) >> 1; if (batch[mid] < t) lo = mid + 1; else hi = mid; }
  starts[t] = lo;
}

// ---------------- Kernel C: scores via bf16 MFMA (unchanged) ----------------
__global__ __launch_bounds__(256) void k_scores(const float* __restrict__ x,
                                                const short* __restrict__ wpack,
                                                const float* __restrict__ W2,
                                                float* __restrict__ scores, int T){
  __shared__ __align__(16) short xs[64 * 128];
  __shared__ float scpart[2][64];
  const int tid  = threadIdx.x;
  const int lane = tid & 63;
  const int w    = tid >> 6;
  const int wm   = w & 1;
  const int wn   = w >> 1;
  const int row0 = blockIdx.x * 64;

#pragma unroll
  for (int it = 0; it < 4; ++it){
    int L  = (it * 256 + tid) * 8;
    int rr = L >> 7;
    int dc = L & 127;
    int grow = row0 + rr; grow = (grow < T) ? grow : (T - 1);
    const float4 v0 = *(const float4*)(x + (size_t)grow * 128 + dc);
    const float4 v1 = *(const float4*)(x + (size_t)grow * 128 + dc + 4);
    short o[8] = {f2bf(v0.x), f2bf(v0.y), f2bf(v0.z), f2bf(v0.w),
                  f2bf(v1.x), f2bf(v1.y), f2bf(v1.z), f2bf(v1.w)};
    int byte = rr * 256 + ((dc * 2) ^ ((rr & 7) << 4));
    *(s16x8*)((char*)xs + byte) = *(const s16x8*)o;
  }
  __syncthreads();

  f32x4 acc[2][8];
#pragma unroll
  for (int mt = 0; mt < 2; ++mt)
#pragma unroll
    for (int kt = 0; kt < 8; ++kt) acc[mt][kt] = (f32x4){0.f, 0.f, 0.f, 0.f};

  const s16x8* wp = (const s16x8*)wpack;
#pragma unroll
  for (int dt = 0; dt < 4; ++dt){
    s16x8 av[2];
#pragma unroll
    for (int mt = 0; mt < 2; ++mt){
      int arow = wm * 32 + mt * 16 + (lane & 15);
      int byte = arow * 256 + ((dt * 64 + (lane >> 4) * 16) ^ ((arow & 7) << 4));
      av[mt] = *(const s16x8*)((const char*)xs + byte);
    }
#pragma unroll
    for (int kt = 0; kt < 8; ++kt){
      s16x8 wv = wp[(size_t)(((wn * 8 + kt) * 4 + dt) << 6) + lane];
#pragma unroll
      for (int mt = 0; mt < 2; ++mt)
        acc[mt][kt] = __builtin_amdgcn_mfma_f32_16x16x32_bf16(av[mt], wv, acc[mt][kt], 0, 0, 0);
    }
  }

  float psum[2][4] = {{0.f,0.f,0.f,0.f},{0.f,0.f,0.f,0.f}};
#pragma unroll
  for (int kt = 0; kt < 8; ++kt){
    const float w2v = W2[(wn * 8 + kt) * 16 + (lane & 15)];
#pragma unroll
    for (int mt = 0; mt < 2; ++mt)
#pragma unroll
      for (int r = 0; r < 4; ++r){
        float a = fminf(fmaxf(acc[mt][kt][r], -15.f), 15.f);
        float e = __expf(2.f * a);
        psum[mt][r] = fmaf((e - 1.f) / (e + 1.f), w2v, psum[mt][r]);
      }
  }
#pragma unroll
  for (int mt = 0; mt < 2; ++mt)
#pragma unroll
    for (int r = 0; r < 4; ++r){
      float v = psum[mt][r];
      v += __shfl_xor(v, 1, 64); v += __shfl_xor(v, 2, 64);
      v += __shfl_xor(v, 4, 64); v += __shfl_xor(v, 8, 64);
      if ((lane & 15) == 0)
        scpart[wn][wm * 32 + mt * 16 + (lane >> 4) * 4 + r] = v;
    }
  __syncthreads();
  if (tid < 64){
    int row = row0 + tid;
    if (row < T) scores[row] = scpart[0][tid] + scpart[1][tid];
  }
}

// ---------------- Kernel D: per-segment UOT-badmm, size-class templated ----------------
// NW=8 handles nb<=64 (512 thr); NW=16 handles nb>64 (1024 thr).
// thread (n = tid>>3, j = tid&7) owns row n, cols j*16..j*16+15.
template<int NW>
__global__ __launch_bounds__(NW * 64, 4) void k_uot(const float* __restrict__ x,
                                                    const int*   __restrict__ starts,
                                                    const float* __restrict__ scores,
                                                    const float* __restrict__ a1r,
                                                    const float* __restrict__ a2r,
                                                    const float* __restrict__ a3r,
                                                    float* __restrict__ out){
  constexpr int PARTS = NW / 2;
  constexpr int RS    = 133;           // odd row stride: combine reads ~2-way
  __shared__ float pbufM[NW][RS];
  __shared__ float pbufS[NW][RS];
  __shared__ float colbuf[128];
  __shared__ float lq0s[128];
  __shared__ float sred[2];

  const int b     = blockIdx.x;
  const int tid   = threadIdx.x;
  const int start = starts[b];
  const int nb    = starts[b + 1] - start;

  if (NW == 8){
    if (nb > 64) return;
    if (nb <= 0){ if (tid < 128) out[(size_t)b * 128 + tid] = 0.f; return; }
  } else {
    if (nb <= 64) return;
  }

  const int n    = tid >> 3;
  const int j    = tid & 7;
  const int wvi  = tid >> 6;
  const int lane = tid & 63;
  const int col  = (NW == 16) ? (tid >> 3) : (tid >> 2);
  const int part = tid & (PARTS - 1);
  const int idxc = (col & 15) * 8 + (col >> 4);

  // ---- segment softmax over scores -> log q0 ----
  if (tid < 128) lq0s[tid] = (tid < nb) ? scores[start + tid] : NEGC;
  __syncthreads();
  if (wvi == 0){
    float v0 = lq0s[lane], v1 = lq0s[lane + 64];
    float m = fmaxf(v0, v1);
#pragma unroll
    for (int msk = 32; msk; msk >>= 1) m = fmaxf(m, __shfl_xor(m, msk, 64));
    float s = __expf(v0 - m) + __expf(v1 - m);
#pragma unroll
    for (int msk = 32; msk; msk >>= 1) s += __shfl_xor(s, msk, 64);
    if (lane == 0){ sred[0] = m; sred[1] = s; }
  }
  __syncthreads();
  const float smax   = sred[0];
  const float sdenom = sred[1] + 1e-16f;
  if (tid < 128){
    float l = NEGC;
    if (tid < nb){
      float qv = __expf(lq0s[tid] - smax) / sdenom;
      l = __logf(qv + 1e-8f);
    }
    lq0s[tid] = l;
  }
  __syncthreads();

  const float a1 = softplusf(a1r[0]);
  const float a2 = softplusf(a2r[0]);
  const float a3 = softplusf(a3r[0]);
  const float inv_a1 = 1.f / a1;
  const float log_p0 = logf(1.0f / 128.0f + 1e-8f);

  float lmu_use[3];
  lmu_use[0] = log_p0;
  {
    float z1 = 0.f, lp = log_p0;
#pragma unroll
    for (int i = 1; i < 3; ++i){
      float nm = (a1 * lp + a2 * log_p0 - z1) / (a1 + a2);
      z1 += a1 * (__expf(nm) - __expf(lp));
      lmu_use[i] = nm; lp = nm;
    }
  }
  const float lq0 = lq0s[n];
  float leta_use[4];
  leta_use[0] = lq0;
  {
    float z2 = 0.f, lp = lq0;
#pragma unroll
    for (int i = 1; i < 4; ++i){
      float nm = (a1 * lp + a3 * lq0 - z2) / (a1 + a3);
      z2 += a1 * (__expf(nm) - __expf(lp));
      leta_use[i] = nm; lp = nm;
    }
  }

  const bool valid = (n < nb);
  float xd[16], z[16], ls[16];
  {
    const float* xp = x + (size_t)(start + n) * 128 + j * 16;
#pragma unroll
    for (int k = 0; k < 16; k += 4){
      float4 v = valid ? *(const float4*)(xp + k) : make_float4(0.f, 0.f, 0.f, 0.f);
      xd[k] = v.x; xd[k+1] = v.y; xd[k+2] = v.z; xd[k+3] = v.w;
    }
    const float lsi = lq0 + log_p0;
#pragma unroll
    for (int k = 0; k < 16; ++k){ z[k] = 0.f; ls[k] = lsi; }
  }

#pragma unroll
  for (int it = 0; it < 4; ++it){
    const float leta_i = leta_use[it];
    float y[16];
    float rmax = -3.402823e38f;
#pragma unroll
    for (int k = 0; k < 16; ++k){
      y[k] = (xd[k] - z[k]) * inv_a1 + ls[k];
      rmax = fmaxf(rmax, y[k]);
    }
    rmax = fmaxf(rmax, __shfl_xor(rmax, 1, 64));
    rmax = fmaxf(rmax, __shfl_xor(rmax, 2, 64));
    rmax = fmaxf(rmax, __shfl_xor(rmax, 4, 64));
    float rsum = 0.f;
#pragma unroll
    for (int k = 0; k < 16; ++k) rsum += __expf(y[k] - rmax);
    rsum += __shfl_xor(rsum, 1, 64);
    rsum += __shfl_xor(rsum, 2, 64);
    rsum += __shfl_xor(rsum, 4, 64);
    const float rlse = rmax + __logf(rsum);
    const float lof  = leta_i - rlse;
#pragma unroll
    for (int k = 0; k < 16; ++k) y[k] += lof;     // y = log_t

    if (it == 3){
      // out[b,d] = 128 * sum_n xd * exp(log_t)
#pragma unroll
      for (int k = 0; k < 16; ++k){
        float v = xd[k] * __expf(y[k]);
        v += __shfl_xor(v, 8, 64);
        v += __shfl_xor(v, 16, 64);
        v += __shfl_xor(v, 32, 64);
        if (lane < 8) pbufS[wvi][k * 8 + lane] = v;
      }
      __syncthreads();
      {
        float s = pbufS[part][idxc] + pbufS[part + PARTS][idxc];
#pragma unroll
        for (int msk = 1; msk < PARTS; msk <<= 1) s += __shfl_xor(s, msk, 64);
        if (part == 0) out[(size_t)b * 128 + col] = 128.f * s;
      }
    } else {
      const float lmu_i = lmu_use[it];
      // wave-local column (max, expsum) partials: y2 = z/a1 + log_t
      float y2[16];
#pragma unroll
      for (int k = 0; k < 16; ++k){
        y2[k] = z[k] * inv_a1 + y[k];
        float m = y2[k];
        m = fmaxf(m, __shfl_xor(m, 8, 64));
        m = fmaxf(m, __shfl_xor(m, 16, 64));
        m = fmaxf(m, __shfl_xor(m, 32, 64));
        float e = __expf(y2[k] - m);
        e += __shfl_xor(e, 8, 64);
        e += __shfl_xor(e, 16, 64);
        e += __shfl_xor(e, 32, 64);
        if (lane < 8){
          pbufM[wvi][k * 8 + lane] = m;
          pbufS[wvi][k * 8 + lane] = e;
        }
      }
      __syncthreads();                             // B1
      // parallel combine: PARTS threads per column, 2 serial + shuffle merge
      {
        float m0 = pbufM[part][idxc],          s0 = pbufS[part][idxc];
        float m1 = pbufM[part + PARTS][idxc],  s1 = pbufS[part + PARTS][idxc];
        float mm = fmaxf(m0, m1);
        float ss = s0 * __expf(m0 - mm) + s1 * __expf(m1 - mm);
#pragma unroll
        for (int msk = 1; msk < PARTS; msk <<= 1){
          float mo = __shfl_xor(mm, msk, 64);
          float so = __shfl_xor(ss, msk, 64);
          float mn = fmaxf(mm, mo);
          ss = ss * __expf(mm - mn) + so * __expf(mo - mn);
          mm = mn;
        }
        if (part == 0) colbuf[col] = mm + __logf(ss);
      }
      __syncthreads();                             // B2
      float cl[16];
      {
        const float4 c0 = *(const float4*)&colbuf[j * 16 + 0];
        const float4 c1 = *(const float4*)&colbuf[j * 16 + 4];
        const float4 c2 = *(const float4*)&colbuf[j * 16 + 8];
        const float4 c3 = *(const float4*)&colbuf[j * 16 + 12];
        cl[0]=c0.x; cl[1]=c0.y; cl[2]=c0.z; cl[3]=c0.w;
        cl[4]=c1.x; cl[5]=c1.y; cl[6]=c1.z; cl[7]=c1.w;
        cl[8]=c2.x; cl[9]=c2.y; cl[10]=c2.z; cl[11]=c2.w;
        cl[12]=c3.x; cl[13]=c3.y; cl[14]=c3.z; cl[15]=c3.w;
      }
#pragma unroll
      for (int k = 0; k < 16; ++k){
        const float lsn = lmu_i + y2[k] - cl[k];
        z[k] += a1 * (__expf(y[k]) - __expf(lsn));
        ls[k] = lsn;
      }
    }
  }
}

extern "C" void kernel_launch(void* const* d_in, const int* in_sizes, int n_in,
                              void* d_out, int out_size, void* d_ws, size_t ws_size,
                              hipStream_t stream){
  const float* x    = (const float*)d_in[0];
  const int*   batch= (const int*)  d_in[1];
  const float* W1   = (const float*)d_in[2];
  const float* W2   = (const float*)d_in[3];
  const float* a1r  = (const float*)d_in[4];
  const float* a2r  = (const float*)d_in[5];
  const float* a3r  = (const float*)d_in[6];
  float* out = (float*)d_out;

  const int T  = in_sizes[1];        // rows of x
  const int Bn = out_size / 128;     // segments

  float* ws     = (float*)d_ws;
  float* scores = ws;                                 // T floats
  short* wpack  = (short*)(ws + ((T + 255) & ~255));  // 32768 bf16
  int*   starts = (int*)(wpack + 32768);              // Bn+1 ints

  k_pack<<<16, 256, 0, stream>>>(W1, wpack);
  k_seg<<<(Bn + 256) / 256, 256, 0, stream>>>(batch, starts, T, Bn);
  const int tiles = (T + 63) / 64;
  k_scores<<<tiles, 256, 0, stream>>>(x, wpack, W2, scores, T);
  k_uot<8><<<Bn, 512, 0, stream>>>(x, starts, scores, a1r, a2r, a3r, out);
  k_uot<16><<<Bn, 1024, 0, stream>>>(x, starts, scores, a1r, a2r, a3r, out);
}

// Round 6
// 121.095 us; speedup vs baseline: 1.8470x; 1.8470x over previous
//
#include <hip/hip_runtime.h>
#include <math.h>

#define NEGC -1000000000.0f

using f32x4 = __attribute__((ext_vector_type(4))) float;
using s16x8 = __attribute__((ext_vector_type(8))) short;

__device__ __forceinline__ float softplusf(float v){ return log1pf(expf(v)); }
__device__ __forceinline__ short f2bf(float f){   // RNE f32->bf16
  unsigned u = __float_as_uint(f);
  unsigned r = (u + 0x7fffu + ((u >> 16) & 1u)) >> 16;
  return (short)r;
}

// ---------------- Kernel A: pack W1 (256x128 f32) into bf16 B-fragments ----------------
__global__ __launch_bounds__(256) void k_pack(const float* __restrict__ W1,
                                              short* __restrict__ wpack){
  int gid  = blockIdx.x * 256 + threadIdx.x;   // 0..4095
  int lane = gid & 63;
  int ft   = gid >> 6;                         // 0..63
  int kt   = ft >> 2;
  int dt   = ft & 3;
  const float* src = W1 + (size_t)(kt * 16 + (lane & 15)) * 128 + dt * 32 + (lane >> 4) * 8;
  short o[8];
#pragma unroll
  for (int e = 0; e < 8; ++e) o[e] = f2bf(src[e]);
  *(s16x8*)(wpack + (size_t)gid * 8) = *(const s16x8*)o;
}

// ---------------- Kernel B: segment starts via parallel binary search ----------------
__global__ __launch_bounds__(256) void k_seg(const int* __restrict__ batch,
                                             int* __restrict__ starts, int T, int Bn){
  int t = blockIdx.x * 256 + threadIdx.x;
  if (t > Bn) return;
  if (t == Bn){ starts[Bn] = T; return; }
  int lo = 0, hi = T;
  while (lo < hi){ int mid = (lo + hi) >> 1; if (batch[mid] < t) lo = mid + 1; else hi = mid; }
  starts[t] = lo;
}

// ---------------- Kernel C: scores via bf16 MFMA (unchanged) ----------------
__global__ __launch_bounds__(256) void k_scores(const float* __restrict__ x,
                                                const short* __restrict__ wpack,
                                                const float* __restrict__ W2,
                                                float* __restrict__ scores, int T){
  __shared__ __align__(16) short xs[64 * 128];
  __shared__ float scpart[2][64];
  const int tid  = threadIdx.x;
  const int lane = tid & 63;
  const int w    = tid >> 6;
  const int wm   = w & 1;
  const int wn   = w >> 1;
  const int row0 = blockIdx.x * 64;

#pragma unroll
  for (int it = 0; it < 4; ++it){
    int L  = (it * 256 + tid) * 8;
    int rr = L >> 7;
    int dc = L & 127;
    int grow = row0 + rr; grow = (grow < T) ? grow : (T - 1);
    const float4 v0 = *(const float4*)(x + (size_t)grow * 128 + dc);
    const float4 v1 = *(const float4*)(x + (size_t)grow * 128 + dc + 4);
    short o[8] = {f2bf(v0.x), f2bf(v0.y), f2bf(v0.z), f2bf(v0.w),
                  f2bf(v1.x), f2bf(v1.y), f2bf(v1.z), f2bf(v1.w)};
    int byte = rr * 256 + ((dc * 2) ^ ((rr & 7) << 4));
    *(s16x8*)((char*)xs + byte) = *(const s16x8*)o;
  }
  __syncthreads();

  f32x4 acc[2][8];
#pragma unroll
  for (int mt = 0; mt < 2; ++mt)
#pragma unroll
    for (int kt = 0; kt < 8; ++kt) acc[mt][kt] = (f32x4){0.f, 0.f, 0.f, 0.f};

  const s16x8* wp = (const s16x8*)wpack;
#pragma unroll
  for (int dt = 0; dt < 4; ++dt){
    s16x8 av[2];
#pragma unroll
    for (int mt = 0; mt < 2; ++mt){
      int arow = wm * 32 + mt * 16 + (lane & 15);
      int byte = arow * 256 + ((dt * 64 + (lane >> 4) * 16) ^ ((arow & 7) << 4));
      av[mt] = *(const s16x8*)((const char*)xs + byte);
    }
#pragma unroll
    for (int kt = 0; kt < 8; ++kt){
      s16x8 wv = wp[(size_t)(((wn * 8 + kt) * 4 + dt) << 6) + lane];
#pragma unroll
      for (int mt = 0; mt < 2; ++mt)
        acc[mt][kt] = __builtin_amdgcn_mfma_f32_16x16x32_bf16(av[mt], wv, acc[mt][kt], 0, 0, 0);
    }
  }

  float psum[2][4] = {{0.f,0.f,0.f,0.f},{0.f,0.f,0.f,0.f}};
#pragma unroll
  for (int kt = 0; kt < 8; ++kt){
    const float w2v = W2[(wn * 8 + kt) * 16 + (lane & 15)];
#pragma unroll
    for (int mt = 0; mt < 2; ++mt)
#pragma unroll
      for (int r = 0; r < 4; ++r){
        float a = fminf(fmaxf(acc[mt][kt][r], -15.f), 15.f);
        float e = __expf(2.f * a);
        psum[mt][r] = fmaf((e - 1.f) / (e + 1.f), w2v, psum[mt][r]);
      }
  }
#pragma unroll
  for (int mt = 0; mt < 2; ++mt)
#pragma unroll
    for (int r = 0; r < 4; ++r){
      float v = psum[mt][r];
      v += __shfl_xor(v, 1, 64); v += __shfl_xor(v, 2, 64);
      v += __shfl_xor(v, 4, 64); v += __shfl_xor(v, 8, 64);
      if ((lane & 15) == 0)
        scpart[wn][wm * 32 + mt * 16 + (lane >> 4) * 4 + r] = v;
    }
  __syncthreads();
  if (tid < 64){
    int row = row0 + tid;
    if (row < T) scores[row] = scpart[0][tid] + scpart[1][tid];
  }
}

// ---------------- Kernel D: per-segment UOT-badmm (single dispatch, runtime NW) ----------
// thread (n = tid>>3, j = tid&7) owns row n, cols j*16..+15.
// No-max softmaxes (range-analysis safe) + exp reuse: exp(log_t)=ey*Et, exp(ls_new)=e2*Emu*rcs.
__global__ __launch_bounds__(1024, 4) void k_uot(const float* __restrict__ x,
                                                 const int*   __restrict__ starts,
                                                 const float* __restrict__ scores,
                                                 const float* __restrict__ a1r,
                                                 const float* __restrict__ a2r,
                                                 const float* __restrict__ a3r,
                                                 float* __restrict__ out){
  __shared__ __align__(16) float pbuf[16][160];   // wave partials: [wv][j*20 + k], 80B-aligned rows
  __shared__ float clseb[128];
  __shared__ float rcsb[128];
  __shared__ float lq0s[128];
  __shared__ float sred[2];

  const int b     = blockIdx.x;
  const int tid   = threadIdx.x;
  const int start = starts[b];
  const int nb    = starts[b + 1] - start;

  if (nb <= 0){
    if (tid < 128) out[(size_t)b * 128 + tid] = 0.f;
    return;
  }
  int amax = nb * 8; if (amax < 128) amax = 128;
  amax = (amax + 63) & ~63;
  if (tid >= amax) return;                 // exited waves; barrier accounts for them
  const int NW = amax >> 6;

  const int n    = tid >> 3;
  const int j    = tid & 7;
  const int wvi  = tid >> 6;
  const int lane = tid & 63;

  // ---- segment softmax over scores -> log q0 (max kept here; raw scores scale unknown) ----
  if (tid < 128) lq0s[tid] = (tid < nb) ? scores[start + tid] : NEGC;
  __syncthreads();
  if (wvi == 0){
    float v0 = lq0s[lane], v1 = lq0s[lane + 64];
    float m = fmaxf(v0, v1);
#pragma unroll
    for (int msk = 32; msk; msk >>= 1) m = fmaxf(m, __shfl_xor(m, msk, 64));
    float s = __expf(v0 - m) + __expf(v1 - m);
#pragma unroll
    for (int msk = 32; msk; msk >>= 1) s += __shfl_xor(s, msk, 64);
    if (lane == 0){ sred[0] = m; sred[1] = s; }
  }
  __syncthreads();
  const float smax   = sred[0];
  const float sdenom = sred[1] + 1e-16f;
  if (tid < 128){
    float l = NEGC;
    if (tid < nb){
      float qv = __expf(lq0s[tid] - smax) / sdenom;
      l = __logf(qv + 1e-8f);
    }
    lq0s[tid] = l;
  }
  __syncthreads();

  const float a1 = softplusf(a1r[0]);
  const float a2 = softplusf(a2r[0]);
  const float a3 = softplusf(a3r[0]);
  const float inv_a1 = 1.f / a1;
  const float log_p0 = logf(1.0f / 128.0f + 1e-8f);

  // mu-recursion (data-independent scalars)
  float lmu_use[3], emu_use[3];
  lmu_use[0] = log_p0;
  {
    float z1 = 0.f, lp = log_p0;
#pragma unroll
    for (int i = 1; i < 3; ++i){
      float nm = (a1 * lp + a2 * log_p0 - z1) / (a1 + a2);
      z1 += a1 * (__expf(nm) - __expf(lp));
      lmu_use[i] = nm; lp = nm;
    }
    emu_use[0] = __expf(lmu_use[0]);
    emu_use[1] = __expf(lmu_use[1]);
    emu_use[2] = __expf(lmu_use[2]);
  }
  // eta-recursion (per-row scalars)
  const float lq0 = lq0s[n];
  float leta_use[4];
  leta_use[0] = lq0;
  {
    float z2 = 0.f, lp = lq0;
#pragma unroll
    for (int i = 1; i < 4; ++i){
      float nm = (a1 * lp + a3 * lq0 - z2) / (a1 + a3);
      z2 += a1 * (__expf(nm) - __expf(lp));
      leta_use[i] = nm; lp = nm;
    }
  }

  const bool valid = (n < nb);
  float xdi[16], zi[16], ls[16];
  {
    const float* xp = x + (size_t)(start + n) * 128 + j * 16;
#pragma unroll
    for (int k = 0; k < 16; k += 4){
      float4 v = valid ? *(const float4*)(xp + k) : make_float4(0.f, 0.f, 0.f, 0.f);
      xdi[k]   = v.x * inv_a1; xdi[k+1] = v.y * inv_a1;
      xdi[k+2] = v.z * inv_a1; xdi[k+3] = v.w * inv_a1;
    }
    const float lsi = lq0 + log_p0;
#pragma unroll
    for (int k = 0; k < 16; ++k){ zi[k] = 0.f; ls[k] = lsi; }
  }

  const int cidx = (tid >> 4) * 20 + (tid & 15);   // combine-phase read index (col=tid)

#pragma unroll
  for (int it = 0; it < 4; ++it){
    // row pass: ey = exp(y_pre), rsum over j-lanes (no max; range-safe)
    float ey[16];
    float rsum = 0.f;
#pragma unroll
    for (int k = 0; k < 16; ++k){
      ey[k] = __expf(xdi[k] - zi[k] + ls[k]);
      rsum += ey[k];
    }
    rsum += __shfl_xor(rsum, 1, 64);
    rsum += __shfl_xor(rsum, 2, 64);
    rsum += __shfl_xor(rsum, 4, 64);
    const float lof = valid ? fminf(leta_use[it] - __logf(rsum), 80.f) : NEGC;
    const float Et  = __expf(lof);

    if (it == 3){
      // out[b,c] = 128 * a1 * sum_n xdi * ey * Et
      float c[16];
#pragma unroll
      for (int k = 0; k < 16; ++k) c[k] = xdi[k] * ey[k] * Et;
#pragma unroll
      for (int lv = 8; lv <= 32; lv <<= 1)
#pragma unroll
        for (int k = 0; k < 16; ++k) c[k] += __shfl_xor(c[k], lv, 64);
      if (lane < 8){
        float* p = &pbuf[wvi][lane * 20];
        *(float4*)(p + 0)  = make_float4(c[0],  c[1],  c[2],  c[3]);
        *(float4*)(p + 4)  = make_float4(c[4],  c[5],  c[6],  c[7]);
        *(float4*)(p + 8)  = make_float4(c[8],  c[9],  c[10], c[11]);
        *(float4*)(p + 12) = make_float4(c[12], c[13], c[14], c[15]);
      }
      __syncthreads();
      if (tid < 128){
        float s = 0.f;
        for (int wq = 0; wq < NW; ++wq) s += pbuf[wq][cidx];
        out[(size_t)b * 128 + tid] = 128.f * a1 * s;
      }
    } else {
      const float lmu_i = lmu_use[it];
      const float Emu   = emu_use[it];
      // col pass: e2 = exp(y2), y2 = xdi + ls + lof; plain column sums
      float e2[16], c[16];
#pragma unroll
      for (int k = 0; k < 16; ++k){
        e2[k] = __expf(xdi[k] + ls[k] + lof);
        c[k]  = e2[k];
      }
#pragma unroll
      for (int lv = 8; lv <= 32; lv <<= 1)
#pragma unroll
        for (int k = 0; k < 16; ++k) c[k] += __shfl_xor(c[k], lv, 64);
      if (lane < 8){
        float* p = &pbuf[wvi][lane * 20];
        *(float4*)(p + 0)  = make_float4(c[0],  c[1],  c[2],  c[3]);
        *(float4*)(p + 4)  = make_float4(c[4],  c[5],  c[6],  c[7]);
        *(float4*)(p + 8)  = make_float4(c[8],  c[9],  c[10], c[11]);
        *(float4*)(p + 12) = make_float4(c[12], c[13], c[14], c[15]);
      }
      __syncthreads();                               // B1
      if (tid < 128){
        float s = 0.f;
        for (int wq = 0; wq < NW; ++wq) s += pbuf[wq][cidx];
        s = fmaxf(s, 1e-30f);
        clseb[tid] = __logf(s);
        rcsb[tid]  = 1.f / s;
      }
      __syncthreads();                               // B2
      float cl[16], rc[16];
      {
        const float4 c0 = *(const float4*)&clseb[j * 16 + 0];
        const float4 c1 = *(const float4*)&clseb[j * 16 + 4];
        const float4 c2 = *(const float4*)&clseb[j * 16 + 8];
        const float4 c3 = *(const float4*)&clseb[j * 16 + 12];
        cl[0]=c0.x; cl[1]=c0.y; cl[2]=c0.z; cl[3]=c0.w;
        cl[4]=c1.x; cl[5]=c1.y; cl[6]=c1.z; cl[7]=c1.w;
        cl[8]=c2.x; cl[9]=c2.y; cl[10]=c2.z; cl[11]=c2.w;
        cl[12]=c3.x; cl[13]=c3.y; cl[14]=c3.z; cl[15]=c3.w;
        const float4 r0 = *(const float4*)&rcsb[j * 16 + 0];
        const float4 r1 = *(const float4*)&rcsb[j * 16 + 4];
        const float4 r2 = *(const float4*)&rcsb[j * 16 + 8];
        const float4 r3 = *(const float4*)&rcsb[j * 16 + 12];
        rc[0]=r0.x; rc[1]=r0.y; rc[2]=r0.z; rc[3]=r0.w;
        rc[4]=r1.x; rc[5]=r1.y; rc[6]=r1.z; rc[7]=r1.w;
        rc[8]=r2.x; rc[9]=r2.y; rc[10]=r2.z; rc[11]=r2.w;
        rc[12]=r3.x; rc[13]=r3.y; rc[14]=r3.z; rc[15]=r3.w;
      }
#pragma unroll
      for (int k = 0; k < 16; ++k){
        const float y2k = xdi[k] + ls[k] + lof;
        ls[k] = lmu_i + y2k - cl[k];
        zi[k] += ey[k] * Et - e2[k] * Emu * rc[k];
      }
    }
  }
}

extern "C" void kernel_launch(void* const* d_in, const int* in_sizes, int n_in,
                              void* d_out, int out_size, void* d_ws, size_t ws_size,
                              hipStream_t stream){
  const float* x    = (const float*)d_in[0];
  const int*   batch= (const int*)  d_in[1];
  const float* W1   = (const float*)d_in[2];
  const float* W2   = (const float*)d_in[3];
  const float* a1r  = (const float*)d_in[4];
  const float* a2r  = (const float*)d_in[5];
  const float* a3r  = (const float*)d_in[6];
  float* out = (float*)d_out;

  const int T  = in_sizes[1];        // rows of x
  const int Bn = out_size / 128;     // segments

  float* ws     = (float*)d_ws;
  float* scores = ws;                                 // T floats
  short* wpack  = (short*)(ws + ((T + 255) & ~255));  // 32768 bf16
  int*   starts = (int*)(wpack + 32768);              // Bn+1 ints

  k_pack<<<16, 256, 0, stream>>>(W1, wpack);
  k_seg<<<(Bn + 256) / 256, 256, 0, stream>>>(batch, starts, T, Bn);
  const int tiles = (T + 63) / 64;
  k_scores<<<tiles, 256, 0, stream>>>(x, wpack, W2, scores, T);
  k_uot<<<Bn, 1024, 0, stream>>>(x, starts, scores, a1r, a2r, a3r, out);
}

// Round 7
// 117.589 us; speedup vs baseline: 1.9021x; 1.0298x over previous
//
#include <hip/hip_runtime.h>
#include <math.h>

#define NEGC -1000000000.0f

using f32x4 = __attribute__((ext_vector_type(4))) float;
using s16x8 = __attribute__((ext_vector_type(8))) short;

__device__ __forceinline__ float softplusf(float v){ return log1pf(expf(v)); }
__device__ __forceinline__ short f2bf(float f){   // RNE f32->bf16
  unsigned u = __float_as_uint(f);
  unsigned r = (u + 0x7fffu + ((u >> 16) & 1u)) >> 16;
  return (short)r;
}

// ---------------- Kernel A: pack W1 (256x128 f32) into bf16 B-fragments ----------------
__global__ __launch_bounds__(256) void k_pack(const float* __restrict__ W1,
                                              short* __restrict__ wpack){
  int gid  = blockIdx.x * 256 + threadIdx.x;   // 0..4095
  int lane = gid & 63;
  int ft   = gid >> 6;                         // 0..63
  int kt   = ft >> 2;
  int dt   = ft & 3;
  const float* src = W1 + (size_t)(kt * 16 + (lane & 15)) * 128 + dt * 32 + (lane >> 4) * 8;
  short o[8];
#pragma unroll
  for (int e = 0; e < 8; ++e) o[e] = f2bf(src[e]);
  *(s16x8*)(wpack + (size_t)gid * 8) = *(const s16x8*)o;
}

// ---------------- Kernel B: segment starts via parallel binary search ----------------
__global__ __launch_bounds__(256) void k_seg(const int* __restrict__ batch,
                                             int* __restrict__ starts, int T, int Bn){
  int t = blockIdx.x * 256 + threadIdx.x;
  if (t > Bn) return;
  if (t == Bn){ starts[Bn] = T; return; }
  int lo = 0, hi = T;
  while (lo < hi){ int mid = (lo + hi) >> 1; if (batch[mid] < t) lo = mid + 1; else hi = mid; }
  starts[t] = lo;
}

// ---------------- Kernel C: scores via bf16 MFMA (unchanged) ----------------
__global__ __launch_bounds__(256) void k_scores(const float* __restrict__ x,
                                                const short* __restrict__ wpack,
                                                const float* __restrict__ W2,
                                                float* __restrict__ scores, int T){
  __shared__ __align__(16) short xs[64 * 128];
  __shared__ float scpart[2][64];
  const int tid  = threadIdx.x;
  const int lane = tid & 63;
  const int w    = tid >> 6;
  const int wm   = w & 1;
  const int wn   = w >> 1;
  const int row0 = blockIdx.x * 64;

#pragma unroll
  for (int it = 0; it < 4; ++it){
    int L  = (it * 256 + tid) * 8;
    int rr = L >> 7;
    int dc = L & 127;
    int grow = row0 + rr; grow = (grow < T) ? grow : (T - 1);
    const float4 v0 = *(const float4*)(x + (size_t)grow * 128 + dc);
    const float4 v1 = *(const float4*)(x + (size_t)grow * 128 + dc + 4);
    short o[8] = {f2bf(v0.x), f2bf(v0.y), f2bf(v0.z), f2bf(v0.w),
                  f2bf(v1.x), f2bf(v1.y), f2bf(v1.z), f2bf(v1.w)};
    int byte = rr * 256 + ((dc * 2) ^ ((rr & 7) << 4));
    *(s16x8*)((char*)xs + byte) = *(const s16x8*)o;
  }
  __syncthreads();

  f32x4 acc[2][8];
#pragma unroll
  for (int mt = 0; mt < 2; ++mt)
#pragma unroll
    for (int kt = 0; kt < 8; ++kt) acc[mt][kt] = (f32x4){0.f, 0.f, 0.f, 0.f};

  const s16x8* wp = (const s16x8*)wpack;
#pragma unroll
  for (int dt = 0; dt < 4; ++dt){
    s16x8 av[2];
#pragma unroll
    for (int mt = 0; mt < 2; ++mt){
      int arow = wm * 32 + mt * 16 + (lane & 15);
      int byte = arow * 256 + ((dt * 64 + (lane >> 4) * 16) ^ ((arow & 7) << 4));
      av[mt] = *(const s16x8*)((const char*)xs + byte);
    }
#pragma unroll
    for (int kt = 0; kt < 8; ++kt){
      s16x8 wv = wp[(size_t)(((wn * 8 + kt) * 4 + dt) << 6) + lane];
#pragma unroll
      for (int mt = 0; mt < 2; ++mt)
        acc[mt][kt] = __builtin_amdgcn_mfma_f32_16x16x32_bf16(av[mt], wv, acc[mt][kt], 0, 0, 0);
    }
  }

  float psum[2][4] = {{0.f,0.f,0.f,0.f},{0.f,0.f,0.f,0.f}};
#pragma unroll
  for (int kt = 0; kt < 8; ++kt){
    const float w2v = W2[(wn * 8 + kt) * 16 + (lane & 15)];
#pragma unroll
    for (int mt = 0; mt < 2; ++mt)
#pragma unroll
      for (int r = 0; r < 4; ++r){
        float a = fminf(fmaxf(acc[mt][kt][r], -15.f), 15.f);
        float e = __expf(2.f * a);
        psum[mt][r] = fmaf((e - 1.f) / (e + 1.f), w2v, psum[mt][r]);
      }
  }
#pragma unroll
  for (int mt = 0; mt < 2; ++mt)
#pragma unroll
    for (int r = 0; r < 4; ++r){
      float v = psum[mt][r];
      v += __shfl_xor(v, 1, 64); v += __shfl_xor(v, 2, 64);
      v += __shfl_xor(v, 4, 64); v += __shfl_xor(v, 8, 64);
      if ((lane & 15) == 0)
        scpart[wn][wm * 32 + mt * 16 + (lane >> 4) * 4 + r] = v;
    }
  __syncthreads();
  if (tid < 64){
    int row = row0 + tid;
    if (row < T) scores[row] = scpart[0][tid] + scpart[1][tid];
  }
}

// ---------------- Kernel D: per-segment UOT-badmm, multiplicative form ----------------
// thread (n = tid>>3, j = tid&7) owns row n, cols j*16..+15.
// State: EX=exp(xd/a1) const, PZ=exp(-z/a1), S=exp(log_s). One exp per elem per iter.
__global__ __launch_bounds__(1024) __attribute__((amdgpu_waves_per_eu(4, 4)))
void k_uot(const float* __restrict__ x,
           const int*   __restrict__ starts,
           const float* __restrict__ scores,
           const float* __restrict__ a1r,
           const float* __restrict__ a2r,
           const float* __restrict__ a3r,
           float* __restrict__ out){
  __shared__ __align__(16) float pbuf[16][164];   // wave partials [wv][j*20+k]; stride 164 (%32==4)
  __shared__ float rcsb[128];
  __shared__ float lq0s[128];
  __shared__ float sred[2];

  const int b     = blockIdx.x;
  const int tid   = threadIdx.x;
  const int start = starts[b];
  const int nb    = starts[b + 1] - start;

  if (nb <= 0){
    if (tid < 128) out[(size_t)b * 128 + tid] = 0.f;
    return;
  }
  int amax = nb * 8; if (amax < 128) amax = 128;
  amax = (amax + 63) & ~63;
  if (tid >= amax) return;                 // exited waves; barrier accounts for them
  const int NW = amax >> 6;
  int pl2 = 8; while ((pl2 << 7) > amax) pl2 >>= 1;   // pow2 threads per column

  const int n    = tid >> 3;
  const int j    = tid & 7;
  const int wvi  = tid >> 6;
  const int lane = tid & 63;
  const int part = tid & (pl2 - 1);
  const int col  = tid / pl2;
  const int cidx = (col >> 4) * 20 + (col & 15);
  const bool cw  = (col < 128);

  // ---- segment softmax over scores -> log q0 ----
  if (tid < 128) lq0s[tid] = (tid < nb) ? scores[start + tid] : NEGC;
  __syncthreads();
  if (wvi == 0){
    float v0 = lq0s[lane], v1 = lq0s[lane + 64];
    float m = fmaxf(v0, v1);
#pragma unroll
    for (int msk = 32; msk; msk >>= 1) m = fmaxf(m, __shfl_xor(m, msk, 64));
    float s = __expf(v0 - m) + __expf(v1 - m);
#pragma unroll
    for (int msk = 32; msk; msk >>= 1) s += __shfl_xor(s, msk, 64);
    if (lane == 0){ sred[0] = m; sred[1] = s; }
  }
  __syncthreads();
  const float smax   = sred[0];
  const float sdenom = sred[1] + 1e-16f;
  if (tid < 128){
    float l = NEGC;
    if (tid < nb){
      float qv = __expf(lq0s[tid] - smax) / sdenom;
      l = __logf(qv + 1e-8f);
    }
    lq0s[tid] = l;
  }
  __syncthreads();

  const float a1 = softplusf(a1r[0]);
  const float a2 = softplusf(a2r[0]);
  const float a3 = softplusf(a3r[0]);
  const float inv_a1 = 1.f / a1;
  const float log_p0 = logf(1.0f / 128.0f + 1e-8f);

  // mu-recursion -> Emu scalars
  float emu_use[3];
  {
    float z1 = 0.f, lp = log_p0;
    emu_use[0] = __expf(log_p0);
#pragma unroll
    for (int i = 1; i < 3; ++i){
      float nm = (a1 * lp + a2 * log_p0 - z1) / (a1 + a2);
      z1 += a1 * (__expf(nm) - __expf(lp));
      emu_use[i] = __expf(nm); lp = nm;
    }
  }
  // eta-recursion -> Eeta scalars (per row)
  const float lq0 = lq0s[n];
  float eeta_use[4];
  {
    float z2 = 0.f, lp = lq0;
    eeta_use[0] = __expf(lq0);
#pragma unroll
    for (int i = 1; i < 4; ++i){
      float nm = (a1 * lp + a3 * lq0 - z2) / (a1 + a3);
      z2 += a1 * (__expf(nm) - __expf(lp));
      eeta_use[i] = __expf(nm); lp = nm;
    }
  }

  const bool valid = (n < nb);
  float xdi[16], EX[16], PZ[16], S[16];
  {
    const float* xp = x + (size_t)(start + n) * 128 + j * 16;
#pragma unroll
    for (int k = 0; k < 16; k += 4){
      float4 v = valid ? *(const float4*)(xp + k) : make_float4(0.f, 0.f, 0.f, 0.f);
      xdi[k]   = v.x * inv_a1; xdi[k+1] = v.y * inv_a1;
      xdi[k+2] = v.z * inv_a1; xdi[k+3] = v.w * inv_a1;
    }
    const float s0 = __expf(lq0 + log_p0);     // 0 for invalid rows
#pragma unroll
    for (int k = 0; k < 16; ++k){
      EX[k] = __expf(xdi[k]);
      PZ[k] = 1.f;
      S[k]  = s0;
    }
  }

#pragma unroll
  for (int it = 0; it < 4; ++it){
    // row pass: t = EX*S*PZ (= exp(y_pre)); rsum over the 8 j-lanes
    float t[16];
    float rsum = 0.f;
#pragma unroll
    for (int k = 0; k < 16; ++k){
      t[k] = EX[k] * S[k] * PZ[k];
      rsum += t[k];
    }
    rsum += __shfl_xor(rsum, 1, 64);
    rsum += __shfl_xor(rsum, 2, 64);
    rsum += __shfl_xor(rsum, 4, 64);
    const float Et = valid ? (eeta_use[it] / rsum) : 0.f;
#pragma unroll
    for (int k = 0; k < 16; ++k) t[k] *= Et;       // t = exp(log_t)

    if (it == 3){
      // out[b,c] = 128 * a1 * sum_n xdi * t
      float c[16];
#pragma unroll
      for (int k = 0; k < 16; ++k) c[k] = xdi[k] * t[k];
#pragma unroll
      for (int lv = 8; lv <= 32; lv <<= 1)
#pragma unroll
        for (int k = 0; k < 16; ++k) c[k] += __shfl_xor(c[k], lv, 64);
      if (lane < 8){
        float* p = &pbuf[wvi][lane * 20];
        *(float4*)(p + 0)  = make_float4(c[0],  c[1],  c[2],  c[3]);
        *(float4*)(p + 4)  = make_float4(c[4],  c[5],  c[6],  c[7]);
        *(float4*)(p + 8)  = make_float4(c[8],  c[9],  c[10], c[11]);
        *(float4*)(p + 12) = make_float4(c[12], c[13], c[14], c[15]);
      }
      __syncthreads();
      if (cw){
        float s = 0.f;
        for (int wq = part; wq < NW; wq += pl2) s += pbuf[wq][cidx];
#pragma unroll
        for (int m = 1; m < 8; m <<= 1){
          if (m < pl2) s += __shfl_xor(s, m, 64);
        }
        if (part == 0) out[(size_t)b * 128 + col] = 128.f * a1 * s;
      }
    } else {
      const float Emu = emu_use[it];
      // col pass: e2 = EX*S*Et (= exp(y2)); plain column sums
      float e2[16], c[16];
#pragma unroll
      for (int k = 0; k < 16; ++k){
        e2[k] = EX[k] * S[k] * Et;
        c[k]  = e2[k];
      }
#pragma unroll
      for (int lv = 8; lv <= 32; lv <<= 1)
#pragma unroll
        for (int k = 0; k < 16; ++k) c[k] += __shfl_xor(c[k], lv, 64);
      if (lane < 8){
        float* p = &pbuf[wvi][lane * 20];
        *(float4*)(p + 0)  = make_float4(c[0],  c[1],  c[2],  c[3]);
        *(float4*)(p + 4)  = make_float4(c[4],  c[5],  c[6],  c[7]);
        *(float4*)(p + 8)  = make_float4(c[8],  c[9],  c[10], c[11]);
        *(float4*)(p + 12) = make_float4(c[12], c[13], c[14], c[15]);
      }
      __syncthreads();                               // B1
      if (cw){
        float s = 0.f;
        for (int wq = part; wq < NW; wq += pl2) s += pbuf[wq][cidx];
#pragma unroll
        for (int m = 1; m < 8; m <<= 1){
          if (m < pl2) s += __shfl_xor(s, m, 64);
        }
        if (part == 0) rcsb[col] = 1.f / fmaxf(s, 1e-30f);
      }
      __syncthreads();                               // B2
      float rc[16];
      {
        const float4 r0 = *(const float4*)&rcsb[j * 16 + 0];
        const float4 r1 = *(const float4*)&rcsb[j * 16 + 4];
        const float4 r2 = *(const float4*)&rcsb[j * 16 + 8];
        const float4 r3 = *(const float4*)&rcsb[j * 16 + 12];
        rc[0]=r0.x; rc[1]=r0.y; rc[2]=r0.z; rc[3]=r0.w;
        rc[4]=r1.x; rc[5]=r1.y; rc[6]=r1.z; rc[7]=r1.w;
        rc[8]=r2.x; rc[9]=r2.y; rc[10]=r2.z; rc[11]=r2.w;
        rc[12]=r3.x; rc[13]=r3.y; rc[14]=r3.z; rc[15]=r3.w;
      }
#pragma unroll
      for (int k = 0; k < 16; ++k){
        const float sn = Emu * e2[k] * rc[k];        // exp(log_s_new)
        PZ[k] *= __expf(sn - t[k]);                  // z += a1*(t - s) -> PZ *= exp(s - t)
        S[k]   = sn;
      }
    }
  }
}

extern "C" void kernel_launch(void* const* d_in, const int* in_sizes, int n_in,
                              void* d_out, int out_size, void* d_ws, size_t ws_size,
                              hipStream_t stream){
  const float* x    = (const float*)d_in[0];
  const int*   batch= (const int*)  d_in[1];
  const float* W1   = (const float*)d_in[2];
  const float* W2   = (const float*)d_in[3];
  const float* a1r  = (const float*)d_in[4];
  const float* a2r  = (const float*)d_in[5];
  const float* a3r  = (const float*)d_in[6];
  float* out = (float*)d_out;

  const int T  = in_sizes[1];        // rows of x
  const int Bn = out_size / 128;     // segments

  float* ws     = (float*)d_ws;
  float* scores = ws;                                 // T floats
  short* wpack  = (short*)(ws + ((T + 255) & ~255));  // 32768 bf16
  int*   starts = (int*)(wpack + 32768);              // Bn+1 ints

  k_pack<<<16, 256, 0, stream>>>(W1, wpack);
  k_seg<<<(Bn + 256) / 256, 256, 0, stream>>>(batch, starts, T, Bn);
  const int tiles = (T + 63) / 64;
  k_scores<<<tiles, 256, 0, stream>>>(x, wpack, W2, scores, T);
  k_uot<<<Bn, 1024, 0, stream>>>(x, starts, scores, a1r, a2r, a3r, out);
}

// Round 8
// 113.785 us; speedup vs baseline: 1.9657x; 1.0334x over previous
//
#include <hip/hip_runtime.h>
#include <math.h>

#define NEGC -1000000000.0f

using f32x4 = __attribute__((ext_vector_type(4))) float;
using s16x8 = __attribute__((ext_vector_type(8))) short;

__device__ __forceinline__ float softplusf(float v){ return log1pf(expf(v)); }
__device__ __forceinline__ short f2bf(float f){   // RNE f32->bf16
  unsigned u = __float_as_uint(f);
  unsigned r = (u + 0x7fffu + ((u >> 16) & 1u)) >> 16;
  return (short)r;
}

// ---------------- Kernel A: pack W1 (256x128 f32) into bf16 B-fragments ----------------
__global__ __launch_bounds__(256) void k_pack(const float* __restrict__ W1,
                                              short* __restrict__ wpack){
  int gid  = blockIdx.x * 256 + threadIdx.x;   // 0..4095
  int lane = gid & 63;
  int ft   = gid >> 6;                         // 0..63
  int kt   = ft >> 2;
  int dt   = ft & 3;
  const float* src = W1 + (size_t)(kt * 16 + (lane & 15)) * 128 + dt * 32 + (lane >> 4) * 8;
  short o[8];
#pragma unroll
  for (int e = 0; e < 8; ++e) o[e] = f2bf(src[e]);
  *(s16x8*)(wpack + (size_t)gid * 8) = *(const s16x8*)o;
}

// ---------------- Kernel B: segment starts via parallel binary search ----------------
__global__ __launch_bounds__(256) void k_seg(const int* __restrict__ batch,
                                             int* __restrict__ starts, int T, int Bn){
  int t = blockIdx.x * 256 + threadIdx.x;
  if (t > Bn) return;
  if (t == Bn){ starts[Bn] = T; return; }
  int lo = 0, hi = T;
  while (lo < hi){ int mid = (lo + hi) >> 1; if (batch[mid] < t) lo = mid + 1; else hi = mid; }
  starts[t] = lo;
}

// ---------------- Kernel C: scores via bf16 MFMA (unchanged) ----------------
__global__ __launch_bounds__(256) void k_scores(const float* __restrict__ x,
                                                const short* __restrict__ wpack,
                                                const float* __restrict__ W2,
                                                float* __restrict__ scores, int T){
  __shared__ __align__(16) short xs[64 * 128];
  __shared__ float scpart[2][64];
  const int tid  = threadIdx.x;
  const int lane = tid & 63;
  const int w    = tid >> 6;
  const int wm   = w & 1;
  const int wn   = w >> 1;
  const int row0 = blockIdx.x * 64;

#pragma unroll
  for (int it = 0; it < 4; ++it){
    int L  = (it * 256 + tid) * 8;
    int rr = L >> 7;
    int dc = L & 127;
    int grow = row0 + rr; grow = (grow < T) ? grow : (T - 1);
    const float4 v0 = *(const float4*)(x + (size_t)grow * 128 + dc);
    const float4 v1 = *(const float4*)(x + (size_t)grow * 128 + dc + 4);
    short o[8] = {f2bf(v0.x), f2bf(v0.y), f2bf(v0.z), f2bf(v0.w),
                  f2bf(v1.x), f2bf(v1.y), f2bf(v1.z), f2bf(v1.w)};
    int byte = rr * 256 + ((dc * 2) ^ ((rr & 7) << 4));
    *(s16x8*)((char*)xs + byte) = *(const s16x8*)o;
  }
  __syncthreads();

  f32x4 acc[2][8];
#pragma unroll
  for (int mt = 0; mt < 2; ++mt)
#pragma unroll
    for (int kt = 0; kt < 8; ++kt) acc[mt][kt] = (f32x4){0.f, 0.f, 0.f, 0.f};

  const s16x8* wp = (const s16x8*)wpack;
#pragma unroll
  for (int dt = 0; dt < 4; ++dt){
    s16x8 av[2];
#pragma unroll
    for (int mt = 0; mt < 2; ++mt){
      int arow = wm * 32 + mt * 16 + (lane & 15);
      int byte = arow * 256 + ((dt * 64 + (lane >> 4) * 16) ^ ((arow & 7) << 4));
      av[mt] = *(const s16x8*)((const char*)xs + byte);
    }
#pragma unroll
    for (int kt = 0; kt < 8; ++kt){
      s16x8 wv = wp[(size_t)(((wn * 8 + kt) * 4 + dt) << 6) + lane];
#pragma unroll
      for (int mt = 0; mt < 2; ++mt)
        acc[mt][kt] = __builtin_amdgcn_mfma_f32_16x16x32_bf16(av[mt], wv, acc[mt][kt], 0, 0, 0);
    }
  }

  float psum[2][4] = {{0.f,0.f,0.f,0.f},{0.f,0.f,0.f,0.f}};
#pragma unroll
  for (int kt = 0; kt < 8; ++kt){
    const float w2v = W2[(wn * 8 + kt) * 16 + (lane & 15)];
#pragma unroll
    for (int mt = 0; mt < 2; ++mt)
#pragma unroll
      for (int r = 0; r < 4; ++r){
        float a = fminf(fmaxf(acc[mt][kt][r], -15.f), 15.f);
        float e = __expf(2.f * a);
        psum[mt][r] = fmaf((e - 1.f) / (e + 1.f), w2v, psum[mt][r]);
      }
  }
#pragma unroll
  for (int mt = 0; mt < 2; ++mt)
#pragma unroll
    for (int r = 0; r < 4; ++r){
      float v = psum[mt][r];
      v += __shfl_xor(v, 1, 64); v += __shfl_xor(v, 2, 64);
      v += __shfl_xor(v, 4, 64); v += __shfl_xor(v, 8, 64);
      if ((lane & 15) == 0)
        scpart[wn][wm * 32 + mt * 16 + (lane >> 4) * 4 + r] = v;
    }
  __syncthreads();
  if (tid < 64){
    int row = row0 + tid;
    if (row < T) scores[row] = scpart[0][tid] + scpart[1][tid];
  }
}

// ---------------- Kernel D: per-segment UOT-badmm, minimal-state multiplicative ----------
// thread (n = tid>>3, j = tid&7) owns row n, cols j*16..+15.
// Persistent state: EX=exp(xd/a1), PZ=exp(-z/a1), S=exp(log_s)  (48 regs).
// Identities: t = EX*S*PZ*Et = e2*PZ;  e2 = EX*S*Et  -> recompute, never keep across barriers.
__global__ __launch_bounds__(1024)
void k_uot(const float* __restrict__ x,
           const int*   __restrict__ starts,
           const float* __restrict__ scores,
           const float* __restrict__ a1r,
           const float* __restrict__ a2r,
           const float* __restrict__ a3r,
           float* __restrict__ out){
  __shared__ __align__(16) float pbuf[16][164];   // wave partials [wv][j*20+k]
  __shared__ float rcsb[128];
  __shared__ float lq0s[128];
  __shared__ float sred[2];

  const int b     = blockIdx.x;
  const int tid   = threadIdx.x;
  const int start = starts[b];
  const int nb    = starts[b + 1] - start;

  if (nb <= 0){
    if (tid < 128) out[(size_t)b * 128 + tid] = 0.f;
    return;
  }
  int amax = nb * 8; if (amax < 128) amax = 128;
  amax = (amax + 63) & ~63;
  if (tid >= amax) return;                 // exited waves; barrier accounts for them
  const int NW = amax >> 6;
  int pl2 = 8; while ((pl2 << 7) > amax) pl2 >>= 1;   // pow2 threads per column

  const int n    = tid >> 3;
  const int j    = tid & 7;
  const int wvi  = tid >> 6;
  const int lane = tid & 63;
  const int part = tid & (pl2 - 1);
  const int col  = tid / pl2;
  const int cidx = (col >> 4) * 20 + (col & 15);
  const bool cw  = (col < 128);

  // ---- segment softmax over scores -> log q0 ----
  if (tid < 128) lq0s[tid] = (tid < nb) ? scores[start + tid] : NEGC;
  __syncthreads();
  if (wvi == 0){
    float v0 = lq0s[lane], v1 = lq0s[lane + 64];
    float m = fmaxf(v0, v1);
#pragma unroll
    for (int msk = 32; msk; msk >>= 1) m = fmaxf(m, __shfl_xor(m, msk, 64));
    float s = __expf(v0 - m) + __expf(v1 - m);
#pragma unroll
    for (int msk = 32; msk; msk >>= 1) s += __shfl_xor(s, msk, 64);
    if (lane == 0){ sred[0] = m; sred[1] = s; }
  }
  __syncthreads();
  const float smax   = sred[0];
  const float sdenom = sred[1] + 1e-16f;
  if (tid < 128){
    float l = NEGC;
    if (tid < nb){
      float qv = __expf(lq0s[tid] - smax) / sdenom;
      l = __logf(qv + 1e-8f);
    }
    lq0s[tid] = l;
  }
  __syncthreads();

  const float a1 = softplusf(a1r[0]);
  const float a2 = softplusf(a2r[0]);
  const float a3 = softplusf(a3r[0]);
  const float inv_a1 = 1.f / a1;
  const float log_p0 = logf(1.0f / 128.0f + 1e-8f);

  // mu-recursion -> Emu scalars (wave-uniform)
  float emu_use[3];
  {
    float z1 = 0.f, lp = log_p0;
    emu_use[0] = __expf(log_p0);
#pragma unroll
    for (int i = 1; i < 3; ++i){
      float nm = (a1 * lp + a2 * log_p0 - z1) / (a1 + a2);
      z1 += a1 * (__expf(nm) - __expf(lp));
      emu_use[i] = __expf(nm); lp = nm;
    }
  }
  // eta-recursion -> Eeta scalars (per row)
  const float lq0 = lq0s[n];
  float eeta_use[4];
  {
    float z2 = 0.f, lp = lq0;
    eeta_use[0] = __expf(lq0);
#pragma unroll
    for (int i = 1; i < 4; ++i){
      float nm = (a1 * lp + a3 * lq0 - z2) / (a1 + a3);
      z2 += a1 * (__expf(nm) - __expf(lp));
      eeta_use[i] = __expf(nm); lp = nm;
    }
  }

  const bool valid = (n < nb);
  const float* xp = x + (size_t)(start + n) * 128 + j * 16;
  float EX[16], PZ[16], S[16];
  {
    const float s0 = __expf(lq0 + log_p0);     // 0 for invalid rows
#pragma unroll
    for (int k = 0; k < 16; k += 4){
      float4 v = valid ? *(const float4*)(xp + k) : make_float4(0.f, 0.f, 0.f, 0.f);
      EX[k]   = __expf(v.x * inv_a1);
      EX[k+1] = __expf(v.y * inv_a1);
      EX[k+2] = __expf(v.z * inv_a1);
      EX[k+3] = __expf(v.w * inv_a1);
    }
#pragma unroll
    for (int k = 0; k < 16; ++k){ PZ[k] = 1.f; S[k] = s0; }
  }

#pragma unroll
  for (int it = 0; it < 4; ++it){
    // row pass: rsum = sum_k EX*S*PZ over this row's 8 lanes
    float rsum = 0.f;
#pragma unroll
    for (int k = 0; k < 16; ++k) rsum += EX[k] * S[k] * PZ[k];
    rsum += __shfl_xor(rsum, 1, 64);
    rsum += __shfl_xor(rsum, 2, 64);
    rsum += __shfl_xor(rsum, 4, 64);
    const float Et = valid ? (eeta_use[it] / rsum) : 0.f;

    if (it == 3){
      // out[b,c] = 128 * sum_n xd * t,  t = EX*S*PZ*Et
      float c[16];
#pragma unroll
      for (int k = 0; k < 16; k += 4){
        float4 v = valid ? *(const float4*)(xp + k) : make_float4(0.f, 0.f, 0.f, 0.f);
        c[k]   = v.x * EX[k]   * S[k]   * PZ[k]   * Et;
        c[k+1] = v.y * EX[k+1] * S[k+1] * PZ[k+1] * Et;
        c[k+2] = v.z * EX[k+2] * S[k+2] * PZ[k+2] * Et;
        c[k+3] = v.w * EX[k+3] * S[k+3] * PZ[k+3] * Et;
      }
#pragma unroll
      for (int lv = 8; lv <= 32; lv <<= 1)
#pragma unroll
        for (int k = 0; k < 16; ++k) c[k] += __shfl_xor(c[k], lv, 64);
      if (lane < 8){
        float* p = &pbuf[wvi][lane * 20];
        *(float4*)(p + 0)  = make_float4(c[0],  c[1],  c[2],  c[3]);
        *(float4*)(p + 4)  = make_float4(c[4],  c[5],  c[6],  c[7]);
        *(float4*)(p + 8)  = make_float4(c[8],  c[9],  c[10], c[11]);
        *(float4*)(p + 12) = make_float4(c[12], c[13], c[14], c[15]);
      }
      __syncthreads();
      if (cw){
        float s = 0.f;
        for (int wq = part; wq < NW; wq += pl2) s += pbuf[wq][cidx];
#pragma unroll
        for (int m = 1; m < 8; m <<= 1){
          if (m < pl2) s += __shfl_xor(s, m, 64);
        }
        if (part == 0) out[(size_t)b * 128 + col] = 128.f * s;
      }
    } else {
      const float Emu = emu_use[it];
      // col pass: column sums of e2 = EX*S*Et
      float c[16];
#pragma unroll
      for (int k = 0; k < 16; ++k) c[k] = EX[k] * S[k] * Et;
#pragma unroll
      for (int lv = 8; lv <= 32; lv <<= 1)
#pragma unroll
        for (int k = 0; k < 16; ++k) c[k] += __shfl_xor(c[k], lv, 64);
      if (lane < 8){
        float* p = &pbuf[wvi][lane * 20];
        *(float4*)(p + 0)  = make_float4(c[0],  c[1],  c[2],  c[3]);
        *(float4*)(p + 4)  = make_float4(c[4],  c[5],  c[6],  c[7]);
        *(float4*)(p + 8)  = make_float4(c[8],  c[9],  c[10], c[11]);
        *(float4*)(p + 12) = make_float4(c[12], c[13], c[14], c[15]);
      }
      __syncthreads();                               // B1
      if (cw){
        float s = 0.f;
        for (int wq = part; wq < NW; wq += pl2) s += pbuf[wq][cidx];
#pragma unroll
        for (int m = 1; m < 8; m <<= 1){
          if (m < pl2) s += __shfl_xor(s, m, 64);
        }
        if (part == 0) rcsb[col] = 1.f / fmaxf(s, 1e-30f);
      }
      __syncthreads();                               // B2
      float rc[16];
      {
        const float4 r0 = *(const float4*)&rcsb[j * 16 + 0];
        const float4 r1 = *(const float4*)&rcsb[j * 16 + 4];
        const float4 r2 = *(const float4*)&rcsb[j * 16 + 8];
        const float4 r3 = *(const float4*)&rcsb[j * 16 + 12];
        rc[0]=r0.x; rc[1]=r0.y; rc[2]=r0.z; rc[3]=r0.w;
        rc[4]=r1.x; rc[5]=r1.y; rc[6]=r1.z; rc[7]=r1.w;
        rc[8]=r2.x; rc[9]=r2.y; rc[10]=r2.z; rc[11]=r2.w;
        rc[12]=r3.x; rc[13]=r3.y; rc[14]=r3.z; rc[15]=r3.w;
      }
#pragma unroll
      for (int k = 0; k < 16; ++k){
        const float e2 = EX[k] * S[k] * Et;          // exp(y2)
        const float sn = Emu * e2 * rc[k];           // exp(log_s_new)
        PZ[k] *= __expf(sn - e2 * PZ[k]);            // t = e2*PZ; z += a1*(t-s)
        S[k]   = sn;
      }
    }
  }
}

extern "C" void kernel_launch(void* const* d_in, const int* in_sizes, int n_in,
                              void* d_out, int out_size, void* d_ws, size_t ws_size,
                              hipStream_t stream){
  const float* x    = (const float*)d_in[0];
  const int*   batch= (const int*)  d_in[1];
  const float* W1   = (const float*)d_in[2];
  const float* W2   = (const float*)d_in[3];
  const float* a1r  = (const float*)d_in[4];
  const float* a2r  = (const float*)d_in[5];
  const float* a3r  = (const float*)d_in[6];
  float* out = (float*)d_out;

  const int T  = in_sizes[1];        // rows of x
  const int Bn = out_size / 128;     // segments

  float* ws     = (float*)d_ws;
  float* scores = ws;                                 // T floats
  short* wpack  = (short*)(ws + ((T + 255) & ~255));  // 32768 bf16
  int*   starts = (int*)(wpack + 32768);              // Bn+1 ints

  k_pack<<<16, 256, 0, stream>>>(W1, wpack);
  k_seg<<<(Bn + 256) / 256, 256, 0, stream>>>(batch, starts, T, Bn);
  const int tiles = (T + 63) / 64;
  k_scores<<<tiles, 256, 0, stream>>>(x, wpack, W2, scores, T);
  k_uot<<<Bn, 1024, 0, stream>>>(x, starts, scores, a1r, a2r, a3r, out);
}

// Round 10
// 106.163 us; speedup vs baseline: 2.1068x; 1.0718x over previous
//
#include <hip/hip_runtime.h>
#include <math.h>

#define NEGC -1000000000.0f

using f32x4 = __attribute__((ext_vector_type(4))) float;
using s16x8 = __attribute__((ext_vector_type(8))) short;

__device__ __forceinline__ float softplusf(float v){ return log1pf(expf(v)); }
__device__ __forceinline__ short f2bf(float f){   // RNE f32->bf16
  unsigned u = __float_as_uint(f);
  unsigned r = (u + 0x7fffu + ((u >> 16) & 1u)) >> 16;
  return (short)r;
}

// xor-32 butterfly step. NOTE: permlane32_swap(v,v) returns r[0]={v_lo,v_lo} --
// r[0] double-counts the low half (round-9 bug). Use the known-good shuffle.
__device__ __forceinline__ float red32(float v){
  return v + __shfl_xor(v, 32, 64);
}

// ---------------- Kernel A: pack W1 into bf16 B-fragments; zero counters ----------------
__global__ __launch_bounds__(256) void k_pack(const float* __restrict__ W1,
                                              short* __restrict__ wpack,
                                              int* __restrict__ cnt){
  if (blockIdx.x == 0 && threadIdx.x < 2) cnt[threadIdx.x] = 0;
  int gid  = blockIdx.x * 256 + threadIdx.x;   // 0..4095
  int lane = gid & 63;
  int ft   = gid >> 6;                         // 0..63
  int kt   = ft >> 2;
  int dt   = ft & 3;
  const float* src = W1 + (size_t)(kt * 16 + (lane & 15)) * 128 + dt * 32 + (lane >> 4) * 8;
  short o[8];
#pragma unroll
  for (int e = 0; e < 8; ++e) o[e] = f2bf(src[e]);
  *(s16x8*)(wpack + (size_t)gid * 8) = *(const s16x8*)o;
}

// ---------------- Kernel B: segment starts + big/small classification ----------------
__global__ __launch_bounds__(256) void k_seg(const int* __restrict__ batch,
                                             int* __restrict__ starts, int T, int Bn,
                                             int* __restrict__ cnt,
                                             int* __restrict__ bigs,
                                             int* __restrict__ smalls){
  int t = blockIdx.x * 256 + threadIdx.x;
  if (t > Bn) return;
  int lo = 0, hi = T;
  while (lo < hi){ int mid = (lo + hi) >> 1; if (batch[mid] < t) lo = mid + 1; else hi = mid; }
  if (t == Bn){ starts[Bn] = T; return; }
  starts[t] = lo;
  int lo2 = lo, hi2 = T;
  while (lo2 < hi2){ int mid = (lo2 + hi2) >> 1; if (batch[mid] <= t) lo2 = mid + 1; else hi2 = mid; }
  int nb = lo2 - lo;
  if (nb > 64) bigs[atomicAdd(&cnt[0], 1)] = t;
  else         smalls[atomicAdd(&cnt[1], 1)] = t;
}

// ---------------- Kernel C: scores via bf16 MFMA (unchanged) ----------------
__global__ __launch_bounds__(256) void k_scores(const float* __restrict__ x,
                                                const short* __restrict__ wpack,
                                                const float* __restrict__ W2,
                                                float* __restrict__ scores, int T){
  __shared__ __align__(16) short xs[64 * 128];
  __shared__ float scpart[2][64];
  const int tid  = threadIdx.x;
  const int lane = tid & 63;
  const int w    = tid >> 6;
  const int wm   = w & 1;
  const int wn   = w >> 1;
  const int row0 = blockIdx.x * 64;

#pragma unroll
  for (int it = 0; it < 4; ++it){
    int L  = (it * 256 + tid) * 8;
    int rr = L >> 7;
    int dc = L & 127;
    int grow = row0 + rr; grow = (grow < T) ? grow : (T - 1);
    const float4 v0 = *(const float4*)(x + (size_t)grow * 128 + dc);
    const float4 v1 = *(const float4*)(x + (size_t)grow * 128 + dc + 4);
    short o[8] = {f2bf(v0.x), f2bf(v0.y), f2bf(v0.z), f2bf(v0.w),
                  f2bf(v1.x), f2bf(v1.y), f2bf(v1.z), f2bf(v1.w)};
    int byte = rr * 256 + ((dc * 2) ^ ((rr & 7) << 4));
    *(s16x8*)((char*)xs + byte) = *(const s16x8*)o;
  }
  __syncthreads();

  f32x4 acc[2][8];
#pragma unroll
  for (int mt = 0; mt < 2; ++mt)
#pragma unroll
    for (int kt = 0; kt < 8; ++kt) acc[mt][kt] = (f32x4){0.f, 0.f, 0.f, 0.f};

  const s16x8* wp = (const s16x8*)wpack;
#pragma unroll
  for (int dt = 0; dt < 4; ++dt){
    s16x8 av[2];
#pragma unroll
    for (int mt = 0; mt < 2; ++mt){
      int arow = wm * 32 + mt * 16 + (lane & 15);
      int byte = arow * 256 + ((dt * 64 + (lane >> 4) * 16) ^ ((arow & 7) << 4));
      av[mt] = *(const s16x8*)((const char*)xs + byte);
    }
#pragma unroll
    for (int kt = 0; kt < 8; ++kt){
      s16x8 wv = wp[(size_t)(((wn * 8 + kt) * 4 + dt) << 6) + lane];
#pragma unroll
      for (int mt = 0; mt < 2; ++mt)
        acc[mt][kt] = __builtin_amdgcn_mfma_f32_16x16x32_bf16(av[mt], wv, acc[mt][kt], 0, 0, 0);
    }
  }

  float psum[2][4] = {{0.f,0.f,0.f,0.f},{0.f,0.f,0.f,0.f}};
#pragma unroll
  for (int kt = 0; kt < 8; ++kt){
    const float w2v = W2[(wn * 8 + kt) * 16 + (lane & 15)];
#pragma unroll
    for (int mt = 0; mt < 2; ++mt)
#pragma unroll
      for (int r = 0; r < 4; ++r){
        float a = fminf(fmaxf(acc[mt][kt][r], -15.f), 15.f);
        float e = __expf(2.f * a);
        psum[mt][r] = fmaf((e - 1.f) / (e + 1.f), w2v, psum[mt][r]);
      }
  }
#pragma unroll
  for (int mt = 0; mt < 2; ++mt)
#pragma unroll
    for (int r = 0; r < 4; ++r){
      float v = psum[mt][r];
      v += __shfl_xor(v, 1, 64); v += __shfl_xor(v, 2, 64);
      v += __shfl_xor(v, 4, 64); v += __shfl_xor(v, 8, 64);
      if ((lane & 15) == 0)
        scpart[wn][wm * 32 + mt * 16 + (lane >> 4) * 4 + r] = v;
    }
  __syncthreads();
  if (tid < 64){
    int row = row0 + tid;
    if (row < T) scores[row] = scpart[0][tid] + scpart[1][tid];
  }
}

// ---------------- Kernel D: UOT-badmm; solo-big or paired-small blocks ----------------
// solo (nb>64): 16 waves, n=tid>>3 (0..127), j=tid&7, PL=8.
// pair: waves 0-7 -> segA, 8-15 -> segB; per half n=tid_l>>3 (0..63), PL=4.
__global__ __launch_bounds__(1024)
void k_uot(const float* __restrict__ x,
           const int*   __restrict__ starts,
           const float* __restrict__ scores,
           const int*   __restrict__ cnt,
           const int*   __restrict__ bigs,
           const int*   __restrict__ smalls,
           const float* __restrict__ a1r,
           const float* __restrict__ a2r,
           const float* __restrict__ a3r,
           float* __restrict__ out){
  __shared__ __align__(16) float pbuf[16][164];
  __shared__ float rcsb[2][128];
  __shared__ float lq0s[2][128];
  __shared__ float sred[2][2];

  const int b   = blockIdx.x;
  const int tid = threadIdx.x;
  const int nbig   = cnt[0];
  const int nsmall = cnt[1];

  bool solo; int seg;
  const int half  = tid >> 9;          // 0/1
  const int tid_l = tid & 511;
  if (b < nbig){
    solo = true; seg = bigs[b];
  } else {
    const int i = (b - nbig) * 2 + half;
    solo = false;
    if ((b - nbig) * 2 >= nsmall) return;          // ghost block
    if (i >= nsmall) return;                       // half B missing -> waves exit
    seg = smalls[i];
  }

  const int start = starts[seg];
  const int nb    = starts[seg + 1] - start;
  const int hh    = solo ? 0 : half;
  const int tl    = solo ? tid : tid_l;            // local thread id within segment group
  const int PL    = solo ? 8 : 4;

  if (nb <= 0){
    if (tl < 128) out[(size_t)seg * 128 + tl] = 0.f;
    return;
  }

  const int n    = tl >> 3;
  const int j    = tl & 7;
  const int wvi  = tid >> 6;                       // global wave id (pbuf row)
  const int lane = tid & 63;
  const int part = tl & (PL - 1);
  const int col  = tl / PL;                        // 0..127
  const int cidx = (col >> 4) * 20 + (col & 15);
  const int wq0  = solo ? 0 : half * 8;
  const int NWh  = solo ? 16 : 8;

  // ---- segment softmax over scores -> log q0 ----
  if (tl < 128) lq0s[hh][tl] = (tl < nb) ? scores[start + tl] : NEGC;
  __syncthreads();
  if ((wvi & 7) == 0 && (!solo || wvi == 0)){
    float v0 = lq0s[hh][lane], v1 = lq0s[hh][lane + 64];
    float m = fmaxf(v0, v1);
#pragma unroll
    for (int msk = 32; msk; msk >>= 1) m = fmaxf(m, __shfl_xor(m, msk, 64));
    float s = __expf(v0 - m) + __expf(v1 - m);
#pragma unroll
    for (int msk = 32; msk; msk >>= 1) s += __shfl_xor(s, msk, 64);
    if (lane == 0){ sred[hh][0] = m; sred[hh][1] = s; }
  }
  __syncthreads();
  const float smax   = sred[hh][0];
  const float sdenom = sred[hh][1] + 1e-16f;
  if (tl < 128){
    float l = NEGC;
    if (tl < nb){
      float qv = __expf(lq0s[hh][tl] - smax) / sdenom;
      l = __logf(qv + 1e-8f);
    }
    lq0s[hh][tl] = l;
  }
  __syncthreads();

  const float a1 = softplusf(a1r[0]);
  const float a2 = softplusf(a2r[0]);
  const float a3 = softplusf(a3r[0]);
  const float inv_a1 = 1.f / a1;
  const float log_p0 = logf(1.0f / 128.0f + 1e-8f);

  float emu_use[3];
  {
    float z1 = 0.f, lp = log_p0;
    emu_use[0] = __expf(log_p0);
#pragma unroll
    for (int i = 1; i < 3; ++i){
      float nm = (a1 * lp + a2 * log_p0 - z1) / (a1 + a2);
      z1 += a1 * (__expf(nm) - __expf(lp));
      emu_use[i] = __expf(nm); lp = nm;
    }
  }
  const float lq0 = lq0s[hh][n];
  float eeta_use[4];
  {
    float z2 = 0.f, lp = lq0;
    eeta_use[0] = __expf(lq0);
#pragma unroll
    for (int i = 1; i < 4; ++i){
      float nm = (a1 * lp + a3 * lq0 - z2) / (a1 + a3);
      z2 += a1 * (__expf(nm) - __expf(lp));
      eeta_use[i] = __expf(nm); lp = nm;
    }
  }

  const bool valid = (n < nb);
  const float* xp = x + (size_t)(start + n) * 128 + j * 16;
  float EX[16], PZ[16], S[16];
  {
    const float s0 = __expf(lq0 + log_p0);     // 0 for invalid rows
#pragma unroll
    for (int k = 0; k < 16; k += 4){
      float4 v = valid ? *(const float4*)(xp + k) : make_float4(0.f, 0.f, 0.f, 0.f);
      EX[k]   = __expf(v.x * inv_a1);
      EX[k+1] = __expf(v.y * inv_a1);
      EX[k+2] = __expf(v.z * inv_a1);
      EX[k+3] = __expf(v.w * inv_a1);
    }
#pragma unroll
    for (int k = 0; k < 16; ++k){ PZ[k] = 1.f; S[k] = s0; }
  }

#pragma unroll
  for (int it = 0; it < 4; ++it){
    float rsum = 0.f;
#pragma unroll
    for (int k = 0; k < 16; ++k) rsum += EX[k] * S[k] * PZ[k];
    rsum += __shfl_xor(rsum, 1, 64);
    rsum += __shfl_xor(rsum, 2, 64);
    rsum += __shfl_xor(rsum, 4, 64);
    const float Et = valid ? (eeta_use[it] / rsum) : 0.f;

    if (it == 3){
      float c[16];
#pragma unroll
      for (int k = 0; k < 16; k += 4){
        float4 v = valid ? *(const float4*)(xp + k) : make_float4(0.f, 0.f, 0.f, 0.f);
        c[k]   = v.x * EX[k]   * S[k]   * PZ[k]   * Et;
        c[k+1] = v.y * EX[k+1] * S[k+1] * PZ[k+1] * Et;
        c[k+2] = v.z * EX[k+2] * S[k+2] * PZ[k+2] * Et;
        c[k+3] = v.w * EX[k+3] * S[k+3] * PZ[k+3] * Et;
      }
#pragma unroll
      for (int k = 0; k < 16; ++k){
        float v = red32(c[k]);
        v += __shfl_xor(v, 16, 64);
        v += __shfl_xor(v, 8, 64);
        c[k] = v;
      }
      if (lane < 8){
        float* p = &pbuf[wvi][lane * 20];
        *(float4*)(p + 0)  = make_float4(c[0],  c[1],  c[2],  c[3]);
        *(float4*)(p + 4)  = make_float4(c[4],  c[5],  c[6],  c[7]);
        *(float4*)(p + 8)  = make_float4(c[8],  c[9],  c[10], c[11]);
        *(float4*)(p + 12) = make_float4(c[12], c[13], c[14], c[15]);
      }
      __syncthreads();
      {
        float s = 0.f;
        for (int wq = wq0 + part; wq < wq0 + NWh; wq += PL) s += pbuf[wq][cidx];
        for (int m = 1; m < PL; m <<= 1) s += __shfl_xor(s, m, 64);
        if (part == 0) out[(size_t)seg * 128 + col] = 128.f * s;
      }
    } else {
      const float Emu = emu_use[it];
      float c[16];
#pragma unroll
      for (int k = 0; k < 16; ++k) c[k] = EX[k] * S[k] * Et;
#pragma unroll
      for (int k = 0; k < 16; ++k){
        float v = red32(c[k]);
        v += __shfl_xor(v, 16, 64);
        v += __shfl_xor(v, 8, 64);
        c[k] = v;
      }
      if (lane < 8){
        float* p = &pbuf[wvi][lane * 20];
        *(float4*)(p + 0)  = make_float4(c[0],  c[1],  c[2],  c[3]);
        *(float4*)(p + 4)  = make_float4(c[4],  c[5],  c[6],  c[7]);
        *(float4*)(p + 8)  = make_float4(c[8],  c[9],  c[10], c[11]);
        *(float4*)(p + 12) = make_float4(c[12], c[13], c[14], c[15]);
      }
      __syncthreads();                               // B1
      {
        float s = 0.f;
        for (int wq = wq0 + part; wq < wq0 + NWh; wq += PL) s += pbuf[wq][cidx];
        for (int m = 1; m < PL; m <<= 1) s += __shfl_xor(s, m, 64);
        if (part == 0) rcsb[hh][col] = 1.f / fmaxf(s, 1e-30f);
      }
      __syncthreads();                               // B2
      float rc[16];
      {
        const float4 r0 = *(const float4*)&rcsb[hh][j * 16 + 0];
        const float4 r1 = *(const float4*)&rcsb[hh][j * 16 + 4];
        const float4 r2 = *(const float4*)&rcsb[hh][j * 16 + 8];
        const float4 r3 = *(const float4*)&rcsb[hh][j * 16 + 12];
        rc[0]=r0.x; rc[1]=r0.y; rc[2]=r0.z; rc[3]=r0.w;
        rc[4]=r1.x; rc[5]=r1.y; rc[6]=r1.z; rc[7]=r1.w;
        rc[8]=r2.x; rc[9]=r2.y; rc[10]=r2.z; rc[11]=r2.w;
        rc[12]=r3.x; rc[13]=r3.y; rc[14]=r3.z; rc[15]=r3.w;
      }
#pragma unroll
      for (int k = 0; k < 16; ++k){
        const float e2 = EX[k] * S[k] * Et;
        const float sn = Emu * e2 * rc[k];
        PZ[k] *= __expf(sn - e2 * PZ[k]);
        S[k]   = sn;
      }
    }
  }
}

extern "C" void kernel_launch(void* const* d_in, const int* in_sizes, int n_in,
                              void* d_out, int out_size, void* d_ws, size_t ws_size,
                              hipStream_t stream){
  const float* x    = (const float*)d_in[0];
  const int*   batch= (const int*)  d_in[1];
  const float* W1   = (const float*)d_in[2];
  const float* W2   = (const float*)d_in[3];
  const float* a1r  = (const float*)d_in[4];
  const float* a2r  = (const float*)d_in[5];
  const float* a3r  = (const float*)d_in[6];
  float* out = (float*)d_out;

  const int T  = in_sizes[1];        // rows of x
  const int Bn = out_size / 128;     // segments

  float* ws     = (float*)d_ws;
  float* scores = ws;                                 // T floats
  short* wpack  = (short*)(ws + ((T + 255) & ~255));  // 32768 bf16
  int*   starts = (int*)(wpack + 32768);              // Bn+1 ints
  int*   cnt    = starts + (Bn + 2);                  // 2 ints
  int*   bigs   = cnt + 2;                            // Bn ints
  int*   smalls = bigs + Bn;                          // Bn ints

  k_pack<<<16, 256, 0, stream>>>(W1, wpack, cnt);
  k_seg<<<(Bn + 256) / 256, 256, 0, stream>>>(batch, starts, T, Bn, cnt, bigs, smalls);
  const int tiles = (T + 63) / 64;
  k_scores<<<tiles, 256, 0, stream>>>(x, wpack, W2, scores, T);
  k_uot<<<Bn, 1024, 0, stream>>>(x, starts, scores, cnt, bigs, smalls, a1r, a2r, a3r, out);
}

// Round 11
// 102.326 us; speedup vs baseline: 2.1858x; 1.0375x over previous
//
#include <hip/hip_runtime.h>
#include <math.h>

#define NEGC -1000000000.0f

using f32x4 = __attribute__((ext_vector_type(4))) float;
using s16x8 = __attribute__((ext_vector_type(8))) short;

__device__ __forceinline__ float softplusf(float v){ return log1pf(expf(v)); }
__device__ __forceinline__ short f2bf(float f){   // RNE f32->bf16
  unsigned u = __float_as_uint(f);
  unsigned r = (u + 0x7fffu + ((u >> 16) & 1u)) >> 16;
  return (short)r;
}
__device__ __forceinline__ float red32(float v){ return v + __shfl_xor(v, 32, 64); }

// ---------------- Kernel A: pack W1 into bf16 B-fragments; zero counters ----------------
__global__ __launch_bounds__(256) void k_pack(const float* __restrict__ W1,
                                              short* __restrict__ wpack,
                                              int* __restrict__ cnt){
  if (blockIdx.x == 0 && threadIdx.x < 2) cnt[threadIdx.x] = 0;
  int gid  = blockIdx.x * 256 + threadIdx.x;   // 0..4095
  int lane = gid & 63;
  int ft   = gid >> 6;                         // 0..63 = kt*4+dt
  int kt   = ft >> 2;
  int dt   = ft & 3;
  const float* src = W1 + (size_t)(kt * 16 + (lane & 15)) * 128 + dt * 32 + (lane >> 4) * 8;
  short o[8];
#pragma unroll
  for (int e = 0; e < 8; ++e) o[e] = f2bf(src[e]);
  *(s16x8*)(wpack + (size_t)gid * 8) = *(const s16x8*)o;
}

// ---------------- Kernel B: segment starts + big/small classification ----------------
__global__ __launch_bounds__(256) void k_seg(const int* __restrict__ batch,
                                             int* __restrict__ starts, int T, int Bn,
                                             int* __restrict__ cnt,
                                             int* __restrict__ bigs,
                                             int* __restrict__ smalls){
  int t = blockIdx.x * 256 + threadIdx.x;
  if (t > Bn) return;
  int lo = 0, hi = T;
  while (lo < hi){ int mid = (lo + hi) >> 1; if (batch[mid] < t) lo = mid + 1; else hi = mid; }
  if (t == Bn){ starts[Bn] = T; return; }
  starts[t] = lo;
  int lo2 = lo, hi2 = T;
  while (lo2 < hi2){ int mid = (lo2 + hi2) >> 1; if (batch[mid] <= t) lo2 = mid + 1; else hi2 = mid; }
  int nb = lo2 - lo;
  if (nb > 64) bigs[atomicAdd(&cnt[0], 1)] = t;
  else         smalls[atomicAdd(&cnt[1], 1)] = t;
}

// ---------------- Kernel C: fused scores-MFMA + segment softmax + UOT-badmm ----------------
// solo (nb>64): one big segment, 16 waves; units u=tid>>9 handle rows u*64..+63.
// pair: unit u == half u handles small segment u (waves u*8..u*8+7).
__global__ __launch_bounds__(1024)
void k_uot(const float* __restrict__ x,
           const int*   __restrict__ starts,
           const int*   __restrict__ cnt,
           const int*   __restrict__ bigs,
           const int*   __restrict__ smalls,
           const short* __restrict__ wpack,
           const float* __restrict__ W2,
           const float* __restrict__ a1r,
           const float* __restrict__ a2r,
           const float* __restrict__ a3r,
           float* __restrict__ out, int T){
  __shared__ __align__(16) short xs[2 * 64 * 128];      // 32 KB: 2 units x 64 rows x 128 bf16
  __shared__ __align__(16) float pbuf[16][164];
  __shared__ float scpart[2][4][64];
  __shared__ float rcsb[2][128];
  __shared__ float lq0s[2][128];
  __shared__ float sred[2][2];

  const int b   = blockIdx.x;
  const int tid = threadIdx.x;
  const int nbig   = cnt[0];
  const int nsmall = cnt[1];

  bool solo; int seg;
  const int half  = tid >> 9;          // 0/1
  const int tid_l = tid & 511;
  if (b < nbig){
    solo = true; seg = bigs[b];
  } else {
    const int i = (b - nbig) * 2 + half;
    solo = false;
    if ((b - nbig) * 2 >= nsmall) return;          // ghost block
    if (i >= nsmall) return;                       // half B missing -> waves exit
    seg = smalls[i];
  }

  const int start = starts[seg];
  const int nb    = starts[seg + 1] - start;
  const int hh    = solo ? 0 : half;
  const int tl    = solo ? tid : tid_l;            // local thread id within segment group
  const int PL    = solo ? 8 : 4;

  if (nb <= 0){
    if (tl < 128) out[(size_t)seg * 128 + tl] = 0.f;
    return;
  }

  const int n    = tl >> 3;
  const int j    = tl & 7;
  const int wvi  = tid >> 6;                       // global wave id
  const int lane = tid & 63;
  const int part = tl & (PL - 1);
  const int col  = tl / PL;                        // 0..127
  const int cidx = (col >> 4) * 20 + (col & 15);
  const int wq0  = solo ? 0 : half * 8;
  const int NWh  = solo ? 16 : 8;

  // ===== Phase 1: stage unit rows as swizzled bf16 =====
  const int u      = tid >> 9;                     // unit (== half when paired)
  const int utid   = tid & 511;
  const int ustart = solo ? (start + u * 64) : start;
#pragma unroll
  for (int itr = 0; itr < 2; ++itr){
    int L  = (itr * 512 + utid) * 8;               // element idx in 64x128 tile
    int rr = L >> 7;
    int dc = L & 127;
    int grow = ustart + rr; grow = (grow < T) ? grow : (T - 1);
    const float4 v0 = *(const float4*)(x + (size_t)grow * 128 + dc);
    const float4 v1 = *(const float4*)(x + (size_t)grow * 128 + dc + 4);
    short o[8] = {f2bf(v0.x), f2bf(v0.y), f2bf(v0.z), f2bf(v0.w),
                  f2bf(v1.x), f2bf(v1.y), f2bf(v1.z), f2bf(v1.w)};
    int byte = u * 16384 + rr * 256 + ((dc * 2) ^ ((rr & 7) << 4));
    *(s16x8*)((char*)xs + byte) = *(const s16x8*)o;
  }
  __syncthreads();

  // ===== Phase 2: scores MFMA: unit's 8 waves, wave lw: wm=lw&1 (32-row half), wn=lw>>1 (64-k group)
  {
    const int lw = wvi & 7;
    const int wm = lw & 1;
    const int wn = lw >> 1;
    f32x4 acc[2][4];
#pragma unroll
    for (int mt = 0; mt < 2; ++mt)
#pragma unroll
      for (int kt = 0; kt < 4; ++kt) acc[mt][kt] = (f32x4){0.f, 0.f, 0.f, 0.f};

    const s16x8* wp = (const s16x8*)wpack;
#pragma unroll
    for (int dt = 0; dt < 4; ++dt){
      s16x8 av[2];
#pragma unroll
      for (int mt = 0; mt < 2; ++mt){
        int arow = wm * 32 + mt * 16 + (lane & 15);
        int byte = u * 16384 + arow * 256 + ((dt * 64 + (lane >> 4) * 16) ^ ((arow & 7) << 4));
        av[mt] = *(const s16x8*)((const char*)xs + byte);
      }
#pragma unroll
      for (int kt = 0; kt < 4; ++kt){
        s16x8 wv = wp[(size_t)((((wn * 4 + kt) * 4 + dt)) << 6) + lane];
#pragma unroll
        for (int mt = 0; mt < 2; ++mt)
          acc[mt][kt] = __builtin_amdgcn_mfma_f32_16x16x32_bf16(av[mt], wv, acc[mt][kt], 0, 0, 0);
      }
    }

    float psum[2][4] = {{0.f,0.f,0.f,0.f},{0.f,0.f,0.f,0.f}};
#pragma unroll
    for (int kt = 0; kt < 4; ++kt){
      const float w2v = W2[(wn * 4 + kt) * 16 + (lane & 15)];
#pragma unroll
      for (int mt = 0; mt < 2; ++mt)
#pragma unroll
        for (int r = 0; r < 4; ++r){
          float a = fminf(fmaxf(acc[mt][kt][r], -15.f), 15.f);
          float e = __expf(2.f * a);
          psum[mt][r] = fmaf((e - 1.f) / (e + 1.f), w2v, psum[mt][r]);
        }
    }
#pragma unroll
    for (int mt = 0; mt < 2; ++mt)
#pragma unroll
      for (int r = 0; r < 4; ++r){
        float v = psum[mt][r];
        v += __shfl_xor(v, 1, 64); v += __shfl_xor(v, 2, 64);
        v += __shfl_xor(v, 4, 64); v += __shfl_xor(v, 8, 64);
        if ((lane & 15) == 0)
          scpart[u][wn][wm * 32 + mt * 16 + (lane >> 4) * 4 + r] = v;
      }
  }
  __syncthreads();

  // ===== Phase 3: combine scores + mask into lq0s =====
  if (tl < 128){
    float sc = NEGC;
    if (tl < nb){
      const int ru = solo ? (tl >> 6) : hh;
      const int rl = tl & 63;
      sc = scpart[ru][0][rl] + scpart[ru][1][rl] + scpart[ru][2][rl] + scpart[ru][3][rl];
    }
    lq0s[hh][tl] = sc;
  }
  __syncthreads();

  // ===== Phase 4: segment softmax -> log q0 (unchanged) =====
  if ((wvi & 7) == 0 && (!solo || wvi == 0)){
    float v0 = lq0s[hh][lane], v1 = lq0s[hh][lane + 64];
    float m = fmaxf(v0, v1);
#pragma unroll
    for (int msk = 32; msk; msk >>= 1) m = fmaxf(m, __shfl_xor(m, msk, 64));
    float s = __expf(v0 - m) + __expf(v1 - m);
#pragma unroll
    for (int msk = 32; msk; msk >>= 1) s += __shfl_xor(s, msk, 64);
    if (lane == 0){ sred[hh][0] = m; sred[hh][1] = s; }
  }
  __syncthreads();
  const float smax   = sred[hh][0];
  const float sdenom = sred[hh][1] + 1e-16f;
  if (tl < 128){
    float l = NEGC;
    if (tl < nb){
      float qv = __expf(lq0s[hh][tl] - smax) / sdenom;
      l = __logf(qv + 1e-8f);
    }
    lq0s[hh][tl] = l;
  }
  __syncthreads();

  // ===== Phase 5: UOT-badmm (unchanged from round 10) =====
  const float a1 = softplusf(a1r[0]);
  const float a2 = softplusf(a2r[0]);
  const float a3 = softplusf(a3r[0]);
  const float inv_a1 = 1.f / a1;
  const float log_p0 = logf(1.0f / 128.0f + 1e-8f);

  float emu_use[3];
  {
    float z1 = 0.f, lp = log_p0;
    emu_use[0] = __expf(log_p0);
#pragma unroll
    for (int i = 1; i < 3; ++i){
      float nm = (a1 * lp + a2 * log_p0 - z1) / (a1 + a2);
      z1 += a1 * (__expf(nm) - __expf(lp));
      emu_use[i] = __expf(nm); lp = nm;
    }
  }
  const float lq0 = lq0s[hh][n];
  float eeta_use[4];
  {
    float z2 = 0.f, lp = lq0;
    eeta_use[0] = __expf(lq0);
#pragma unroll
    for (int i = 1; i < 4; ++i){
      float nm = (a1 * lp + a3 * lq0 - z2) / (a1 + a3);
      z2 += a1 * (__expf(nm) - __expf(lp));
      eeta_use[i] = __expf(nm); lp = nm;
    }
  }

  const bool valid = (n < nb);
  const float* xp = x + (size_t)(start + n) * 128 + j * 16;
  float EX[16], PZ[16], S[16];
  {
    const float s0 = __expf(lq0 + log_p0);     // 0 for invalid rows
#pragma unroll
    for (int k = 0; k < 16; k += 4){
      float4 v = valid ? *(const float4*)(xp + k) : make_float4(0.f, 0.f, 0.f, 0.f);
      EX[k]   = __expf(v.x * inv_a1);
      EX[k+1] = __expf(v.y * inv_a1);
      EX[k+2] = __expf(v.z * inv_a1);
      EX[k+3] = __expf(v.w * inv_a1);
    }
#pragma unroll
    for (int k = 0; k < 16; ++k){ PZ[k] = 1.f; S[k] = s0; }
  }

#pragma unroll
  for (int it = 0; it < 4; ++it){
    float rsum = 0.f;
#pragma unroll
    for (int k = 0; k < 16; ++k) rsum += EX[k] * S[k] * PZ[k];
    rsum += __shfl_xor(rsum, 1, 64);
    rsum += __shfl_xor(rsum, 2, 64);
    rsum += __shfl_xor(rsum, 4, 64);
    const float Et = valid ? (eeta_use[it] / rsum) : 0.f;

    if (it == 3){
      float c[16];
#pragma unroll
      for (int k = 0; k < 16; k += 4){
        float4 v = valid ? *(const float4*)(xp + k) : make_float4(0.f, 0.f, 0.f, 0.f);
        c[k]   = v.x * EX[k]   * S[k]   * PZ[k]   * Et;
        c[k+1] = v.y * EX[k+1] * S[k+1] * PZ[k+1] * Et;
        c[k+2] = v.z * EX[k+2] * S[k+2] * PZ[k+2] * Et;
        c[k+3] = v.w * EX[k+3] * S[k+3] * PZ[k+3] * Et;
      }
#pragma unroll
      for (int k = 0; k < 16; ++k){
        float v = red32(c[k]);
        v += __shfl_xor(v, 16, 64);
        v += __shfl_xor(v, 8, 64);
        c[k] = v;
      }
      if (lane < 8){
        float* p = &pbuf[wvi][lane * 20];
        *(float4*)(p + 0)  = make_float4(c[0],  c[1],  c[2],  c[3]);
        *(float4*)(p + 4)  = make_float4(c[4],  c[5],  c[6],  c[7]);
        *(float4*)(p + 8)  = make_float4(c[8],  c[9],  c[10], c[11]);
        *(float4*)(p + 12) = make_float4(c[12], c[13], c[14], c[15]);
      }
      __syncthreads();
      {
        float s = 0.f;
        for (int wq = wq0 + part; wq < wq0 + NWh; wq += PL) s += pbuf[wq][cidx];
        for (int m = 1; m < PL; m <<= 1) s += __shfl_xor(s, m, 64);
        if (part == 0) out[(size_t)seg * 128 + col] = 128.f * s;
      }
    } else {
      const float Emu = emu_use[it];
      float c[16];
#pragma unroll
      for (int k = 0; k < 16; ++k) c[k] = EX[k] * S[k] * Et;
#pragma unroll
      for (int k = 0; k < 16; ++k){
        float v = red32(c[k]);
        v += __shfl_xor(v, 16, 64);
        v += __shfl_xor(v, 8, 64);
        c[k] = v;
      }
      if (lane < 8){
        float* p = &pbuf[wvi][lane * 20];
        *(float4*)(p + 0)  = make_float4(c[0],  c[1],  c[2],  c[3]);
        *(float4*)(p + 4)  = make_float4(c[4],  c[5],  c[6],  c[7]);
        *(float4*)(p + 8)  = make_float4(c[8],  c[9],  c[10], c[11]);
        *(float4*)(p + 12) = make_float4(c[12], c[13], c[14], c[15]);
      }
      __syncthreads();                               // B1
      {
        float s = 0.f;
        for (int wq = wq0 + part; wq < wq0 + NWh; wq += PL) s += pbuf[wq][cidx];
        for (int m = 1; m < PL; m <<= 1) s += __shfl_xor(s, m, 64);
        if (part == 0) rcsb[hh][col] = 1.f / fmaxf(s, 1e-30f);
      }
      __syncthreads();                               // B2
      float rc[16];
      {
        const float4 r0 = *(const float4*)&rcsb[hh][j * 16 + 0];
        const float4 r1 = *(const float4*)&rcsb[hh][j * 16 + 4];
        const float4 r2 = *(const float4*)&rcsb[hh][j * 16 + 8];
        const float4 r3 = *(const float4*)&rcsb[hh][j * 16 + 12];
        rc[0]=r0.x; rc[1]=r0.y; rc[2]=r0.z; rc[3]=r0.w;
        rc[4]=r1.x; rc[5]=r1.y; rc[6]=r1.z; rc[7]=r1.w;
        rc[8]=r2.x; rc[9]=r2.y; rc[10]=r2.z; rc[11]=r2.w;
        rc[12]=r3.x; rc[13]=r3.y; rc[14]=r3.z; rc[15]=r3.w;
      }
#pragma unroll
      for (int k = 0; k < 16; ++k){
        const float e2 = EX[k] * S[k] * Et;
        const float sn = Emu * e2 * rc[k];
        PZ[k] *= __expf(sn - e2 * PZ[k]);
        S[k]   = sn;
      }
    }
  }
}

extern "C" void kernel_launch(void* const* d_in, const int* in_sizes, int n_in,
                              void* d_out, int out_size, void* d_ws, size_t ws_size,
                              hipStream_t stream){
  const float* x    = (const float*)d_in[0];
  const int*   batch= (const int*)  d_in[1];
  const float* W1   = (const float*)d_in[2];
  const float* W2   = (const float*)d_in[3];
  const float* a1r  = (const float*)d_in[4];
  const float* a2r  = (const float*)d_in[5];
  const float* a3r  = (const float*)d_in[6];
  float* out = (float*)d_out;

  const int T  = in_sizes[1];        // rows of x
  const int Bn = out_size / 128;     // segments

  short* wpack  = (short*)d_ws;                       // 32768 bf16
  int*   starts = (int*)(wpack + 32768);              // Bn+1 ints
  int*   cnt    = starts + (Bn + 2);                  // 2 ints
  int*   bigs   = cnt + 2;                            // Bn ints
  int*   smalls = bigs + Bn;                          // Bn ints

  k_pack<<<16, 256, 0, stream>>>(W1, wpack, cnt);
  k_seg<<<(Bn + 256) / 256, 256, 0, stream>>>(batch, starts, T, Bn, cnt, bigs, smalls);
  k_uot<<<Bn, 1024, 0, stream>>>(x, starts, cnt, bigs, smalls, wpack, W2,
                                 a1r, a2r, a3r, out, T);
}

// Round 12
// 92.167 us; speedup vs baseline: 2.4267x; 1.1102x over previous
//
#include <hip/hip_runtime.h>
#include <math.h>

#define NEGC -1000000000.0f

using f32x2 = __attribute__((ext_vector_type(2))) float;
using f32x4 = __attribute__((ext_vector_type(4))) float;
using s16x8 = __attribute__((ext_vector_type(8))) short;

__device__ __forceinline__ float softplusf(float v){ return log1pf(expf(v)); }
__device__ __forceinline__ short f2bf(float f){   // RNE f32->bf16
  unsigned u = __float_as_uint(f);
  unsigned r = (u + 0x7fffu + ((u >> 16) & 1u)) >> 16;
  return (short)r;
}
__device__ __forceinline__ float red32(float v){ return v + __shfl_xor(v, 32, 64); }
__device__ __forceinline__ float frcp(float v){ return __builtin_amdgcn_rcpf(v); }

// ---------------- Kernel A: pack W1 into bf16 B-fragments; zero counters ----------------
__global__ __launch_bounds__(256) void k_pack(const float* __restrict__ W1,
                                              short* __restrict__ wpack,
                                              int* __restrict__ cnt){
  if (blockIdx.x == 0 && threadIdx.x < 2) cnt[threadIdx.x] = 0;
  int gid  = blockIdx.x * 256 + threadIdx.x;   // 0..4095
  int lane = gid & 63;
  int ft   = gid >> 6;                         // 0..63 = kt*4+dt
  int kt   = ft >> 2;
  int dt   = ft & 3;
  const float* src = W1 + (size_t)(kt * 16 + (lane & 15)) * 128 + dt * 32 + (lane >> 4) * 8;
  short o[8];
#pragma unroll
  for (int e = 0; e < 8; ++e) o[e] = f2bf(src[e]);
  *(s16x8*)(wpack + (size_t)gid * 8) = *(const s16x8*)o;
}

// ---------------- Kernel B: segment starts + big/small classification ----------------
__global__ __launch_bounds__(256) void k_seg(const int* __restrict__ batch,
                                             int* __restrict__ starts, int T, int Bn,
                                             int* __restrict__ cnt,
                                             int* __restrict__ bigs,
                                             int* __restrict__ smalls){
  int t = blockIdx.x * 256 + threadIdx.x;
  if (t > Bn) return;
  int lo = 0, hi = T;
  while (lo < hi){ int mid = (lo + hi) >> 1; if (batch[mid] < t) lo = mid + 1; else hi = mid; }
  if (t == Bn){ starts[Bn] = T; return; }
  starts[t] = lo;
  int lo2 = lo, hi2 = T;
  while (lo2 < hi2){ int mid = (lo2 + hi2) >> 1; if (batch[mid] <= t) lo2 = mid + 1; else hi2 = mid; }
  int nb = lo2 - lo;
  if (nb > 64) bigs[atomicAdd(&cnt[0], 1)] = t;
  else         smalls[atomicAdd(&cnt[1], 1)] = t;
}

// ---------------- Kernel C: fused scores-MFMA + segment softmax + UOT-badmm ----------------
__global__ __launch_bounds__(1024)
void k_uot(const float* __restrict__ x,
           const int*   __restrict__ starts,
           const int*   __restrict__ cnt,
           const int*   __restrict__ bigs,
           const int*   __restrict__ smalls,
           const short* __restrict__ wpack,
           const float* __restrict__ W2,
           const float* __restrict__ a1r,
           const float* __restrict__ a2r,
           const float* __restrict__ a3r,
           float* __restrict__ out, int T){
  __shared__ __align__(16) short xs[2 * 64 * 128];      // 32 KB
  __shared__ __align__(16) float pbuf[16][164];
  __shared__ float scpart[2][4][64];
  __shared__ float rcsb[2][128];
  __shared__ float lq0s[2][128];
  __shared__ float sred[2][2];

  const int b   = blockIdx.x;
  const int tid = threadIdx.x;
  const int nbig   = cnt[0];
  const int nsmall = cnt[1];

  bool solo; int seg;
  const int half  = tid >> 9;          // 0/1
  const int tid_l = tid & 511;
  if (b < nbig){
    solo = true; seg = bigs[b];
  } else {
    const int i = (b - nbig) * 2 + half;
    solo = false;
    if ((b - nbig) * 2 >= nsmall) return;          // ghost block
    if (i >= nsmall) return;                       // half B missing -> waves exit
    seg = smalls[i];
  }

  const int start = starts[seg];
  const int nb    = starts[seg + 1] - start;
  const int hh    = solo ? 0 : half;
  const int tl    = solo ? tid : tid_l;
  const int PL    = solo ? 8 : 4;

  if (nb <= 0){
    if (tl < 128) out[(size_t)seg * 128 + tl] = 0.f;
    return;
  }

  const int n    = tl >> 3;
  const int j    = tl & 7;
  const int wvi  = tid >> 6;
  const int lane = tid & 63;
  const int part = tl & (PL - 1);
  const int col  = tl / PL;
  const int cidx = (col >> 4) * 20 + (col & 15);
  const int wq0  = solo ? 0 : half * 8;
  const int NWh  = solo ? 16 : 8;

  // ===== Phase 1: stage unit rows as swizzled bf16 =====
  const int u      = tid >> 9;
  const int utid   = tid & 511;
  const int ustart = solo ? (start + u * 64) : start;
#pragma unroll
  for (int itr = 0; itr < 2; ++itr){
    int L  = (itr * 512 + utid) * 8;
    int rr = L >> 7;
    int dc = L & 127;
    int grow = ustart + rr; grow = (grow < T) ? grow : (T - 1);
    const float4 v0 = *(const float4*)(x + (size_t)grow * 128 + dc);
    const float4 v1 = *(const float4*)(x + (size_t)grow * 128 + dc + 4);
    short o[8] = {f2bf(v0.x), f2bf(v0.y), f2bf(v0.z), f2bf(v0.w),
                  f2bf(v1.x), f2bf(v1.y), f2bf(v1.z), f2bf(v1.w)};
    int byte = u * 16384 + rr * 256 + ((dc * 2) ^ ((rr & 7) << 4));
    *(s16x8*)((char*)xs + byte) = *(const s16x8*)o;
  }
  __syncthreads();

  // ===== Phase 2: scores MFMA =====
  {
    const int lw = wvi & 7;
    const int wm = lw & 1;
    const int wn = lw >> 1;
    f32x4 acc[2][4];
#pragma unroll
    for (int mt = 0; mt < 2; ++mt)
#pragma unroll
      for (int kt = 0; kt < 4; ++kt) acc[mt][kt] = (f32x4){0.f, 0.f, 0.f, 0.f};

    const s16x8* wp = (const s16x8*)wpack;
#pragma unroll
    for (int dt = 0; dt < 4; ++dt){
      s16x8 av[2];
#pragma unroll
      for (int mt = 0; mt < 2; ++mt){
        int arow = wm * 32 + mt * 16 + (lane & 15);
        int byte = u * 16384 + arow * 256 + ((dt * 64 + (lane >> 4) * 16) ^ ((arow & 7) << 4));
        av[mt] = *(const s16x8*)((const char*)xs + byte);
      }
#pragma unroll
      for (int kt = 0; kt < 4; ++kt){
        s16x8 wv = wp[(size_t)((((wn * 4 + kt) * 4 + dt)) << 6) + lane];
#pragma unroll
        for (int mt = 0; mt < 2; ++mt)
          acc[mt][kt] = __builtin_amdgcn_mfma_f32_16x16x32_bf16(av[mt], wv, acc[mt][kt], 0, 0, 0);
      }
    }

    float psum[2][4] = {{0.f,0.f,0.f,0.f},{0.f,0.f,0.f,0.f}};
#pragma unroll
    for (int kt = 0; kt < 4; ++kt){
      const float w2v = W2[(wn * 4 + kt) * 16 + (lane & 15)];
#pragma unroll
      for (int mt = 0; mt < 2; ++mt)
#pragma unroll
        for (int r = 0; r < 4; ++r){
          float e = __expf(2.f * acc[mt][kt][r]);          // |acc|<~10 for this data
          psum[mt][r] = fmaf((e - 1.f) * frcp(e + 1.f), w2v, psum[mt][r]);
        }
    }
#pragma unroll
    for (int mt = 0; mt < 2; ++mt)
#pragma unroll
      for (int r = 0; r < 4; ++r){
        float v = psum[mt][r];
        v += __shfl_xor(v, 1, 64); v += __shfl_xor(v, 2, 64);
        v += __shfl_xor(v, 4, 64); v += __shfl_xor(v, 8, 64);
        if ((lane & 15) == 0)
          scpart[u][wn][wm * 32 + mt * 16 + (lane >> 4) * 4 + r] = v;
      }
  }
  __syncthreads();

  // ===== Phase 3: combine scores + mask into lq0s =====
  if (tl < 128){
    float sc = NEGC;
    if (tl < nb){
      const int ru = solo ? (tl >> 6) : hh;
      const int rl = tl & 63;
      sc = scpart[ru][0][rl] + scpart[ru][1][rl] + scpart[ru][2][rl] + scpart[ru][3][rl];
    }
    lq0s[hh][tl] = sc;
  }
  __syncthreads();

  // ===== Phase 4: segment softmax -> log q0 =====
  if ((wvi & 7) == 0 && (!solo || wvi == 0)){
    float v0 = lq0s[hh][lane], v1 = lq0s[hh][lane + 64];
    float m = fmaxf(v0, v1);
#pragma unroll
    for (int msk = 32; msk; msk >>= 1) m = fmaxf(m, __shfl_xor(m, msk, 64));
    float s = __expf(v0 - m) + __expf(v1 - m);
#pragma unroll
    for (int msk = 32; msk; msk >>= 1) s += __shfl_xor(s, msk, 64);
    if (lane == 0){ sred[hh][0] = m; sred[hh][1] = s; }
  }
  __syncthreads();
  const float smax = sred[hh][0];
  const float rden = frcp(sred[hh][1] + 1e-16f);
  if (tl < 128){
    float l = NEGC;
    if (tl < nb) l = __logf(__expf(lq0s[hh][tl] - smax) * rden + 1e-8f);
    lq0s[hh][tl] = l;
  }
  __syncthreads();

  // ===== Phase 5: UOT-badmm (f32x2-packed) =====
  const float a1 = softplusf(a1r[0]);
  const float a2 = softplusf(a2r[0]);
  const float a3 = softplusf(a3r[0]);
  const float inv_a1 = 1.f / a1;
  const float log_p0 = logf(1.0f / 128.0f + 1e-8f);

  float emu_use[3];
  {
    float z1 = 0.f, lp = log_p0;
    emu_use[0] = __expf(log_p0);
#pragma unroll
    for (int i = 1; i < 3; ++i){
      float nm = (a1 * lp + a2 * log_p0 - z1) / (a1 + a2);
      z1 += a1 * (__expf(nm) - __expf(lp));
      emu_use[i] = __expf(nm); lp = nm;
    }
  }
  const float lq0 = lq0s[hh][n];
  float eeta_use[4];
  {
    float z2 = 0.f, lp = lq0;
    eeta_use[0] = __expf(lq0);
#pragma unroll
    for (int i = 1; i < 4; ++i){
      float nm = (a1 * lp + a3 * lq0 - z2) / (a1 + a3);
      z2 += a1 * (__expf(nm) - __expf(lp));
      eeta_use[i] = __expf(nm); lp = nm;
    }
  }

  const bool valid = (n < nb);
  const int  nc    = valid ? n : (nb - 1);
  const float* xp  = x + (size_t)(start + nc) * 128 + j * 16;   // always in-bounds
  f32x2 EX2[8], PZ2[8], S2[8];
  {
    const float s0 = __expf(lq0 + log_p0);     // exactly 0 for invalid rows (lq0=NEGC)
#pragma unroll
    for (int p = 0; p < 8; p += 2){
      float4 v = *(const float4*)(xp + p * 2);
      EX2[p]   = (f32x2){__expf(v.x * inv_a1), __expf(v.y * inv_a1)};
      EX2[p+1] = (f32x2){__expf(v.z * inv_a1), __expf(v.w * inv_a1)};
    }
#pragma unroll
    for (int p = 0; p < 8; ++p){ PZ2[p] = (f32x2){1.f, 1.f}; S2[p] = (f32x2){s0, s0}; }
  }

#pragma unroll
  for (int it = 0; it < 4; ++it){
    f32x2 ES2[8];
    f32x2 rs2 = (f32x2){0.f, 0.f};
#pragma unroll
    for (int p = 0; p < 8; ++p){
      ES2[p] = EX2[p] * S2[p];
      rs2 += ES2[p] * PZ2[p];
    }
    float rsum = rs2[0] + rs2[1];
    rsum += __shfl_xor(rsum, 1, 64);
    rsum += __shfl_xor(rsum, 2, 64);
    rsum += __shfl_xor(rsum, 4, 64);
    const float Et = valid ? (eeta_use[it] * frcp(rsum)) : 0.f;
    const f32x2 Et2 = (f32x2){Et, Et};

    if (it == 3){
      float c[16];
#pragma unroll
      for (int p = 0; p < 8; p += 2){
        float4 v = *(const float4*)(xp + p * 2);
        f32x2 t0 = ES2[p]   * PZ2[p]   * Et2;
        f32x2 t1 = ES2[p+1] * PZ2[p+1] * Et2;
        c[p*2+0] = v.x * t0[0]; c[p*2+1] = v.y * t0[1];
        c[p*2+2] = v.z * t1[0]; c[p*2+3] = v.w * t1[1];
      }
#pragma unroll
      for (int k = 0; k < 16; ++k){
        float v = red32(c[k]);
        v += __shfl_xor(v, 16, 64);
        v += __shfl_xor(v, 8, 64);
        c[k] = v;
      }
      if (lane < 8){
        float* p = &pbuf[wvi][lane * 20];
        *(float4*)(p + 0)  = make_float4(c[0],  c[1],  c[2],  c[3]);
        *(float4*)(p + 4)  = make_float4(c[4],  c[5],  c[6],  c[7]);
        *(float4*)(p + 8)  = make_float4(c[8],  c[9],  c[10], c[11]);
        *(float4*)(p + 12) = make_float4(c[12], c[13], c[14], c[15]);
      }
      __syncthreads();
      {
        float s = 0.f;
        for (int wq = wq0 + part; wq < wq0 + NWh; wq += PL) s += pbuf[wq][cidx];
        for (int m = 1; m < PL; m <<= 1) s += __shfl_xor(s, m, 64);
        if (part == 0) out[(size_t)seg * 128 + col] = 128.f * s;
      }
    } else {
      const f32x2 Emu2 = (f32x2){emu_use[it], emu_use[it]};
      float c[16];
#pragma unroll
      for (int p = 0; p < 8; ++p){
        f32x2 e2 = ES2[p] * Et2;
        c[p*2+0] = e2[0]; c[p*2+1] = e2[1];
      }
#pragma unroll
      for (int k = 0; k < 16; ++k){
        float v = red32(c[k]);
        v += __shfl_xor(v, 16, 64);
        v += __shfl_xor(v, 8, 64);
        c[k] = v;
      }
      if (lane < 8){
        float* p = &pbuf[wvi][lane * 20];
        *(float4*)(p + 0)  = make_float4(c[0],  c[1],  c[2],  c[3]);
        *(float4*)(p + 4)  = make_float4(c[4],  c[5],  c[6],  c[7]);
        *(float4*)(p + 8)  = make_float4(c[8],  c[9],  c[10], c[11]);
        *(float4*)(p + 12) = make_float4(c[12], c[13], c[14], c[15]);
      }
      __syncthreads();                               // B1
      {
        float s = 0.f;
        for (int wq = wq0 + part; wq < wq0 + NWh; wq += PL) s += pbuf[wq][cidx];
        for (int m = 1; m < PL; m <<= 1) s += __shfl_xor(s, m, 64);
        if (part == 0) rcsb[hh][col] = frcp(fmaxf(s, 1e-30f));
      }
      __syncthreads();                               // B2
      f32x2 rc2[8];
      {
        const float4 r0 = *(const float4*)&rcsb[hh][j * 16 + 0];
        const float4 r1 = *(const float4*)&rcsb[hh][j * 16 + 4];
        const float4 r2 = *(const float4*)&rcsb[hh][j * 16 + 8];
        const float4 r3 = *(const float4*)&rcsb[hh][j * 16 + 12];
        rc2[0] = (f32x2){r0.x, r0.y}; rc2[1] = (f32x2){r0.z, r0.w};
        rc2[2] = (f32x2){r1.x, r1.y}; rc2[3] = (f32x2){r1.z, r1.w};
        rc2[4] = (f32x2){r2.x, r2.y}; rc2[5] = (f32x2){r2.z, r2.w};
        rc2[6] = (f32x2){r3.x, r3.y}; rc2[7] = (f32x2){r3.z, r3.w};
      }
#pragma unroll
      for (int p = 0; p < 8; ++p){
        f32x2 e2 = ES2[p] * Et2;
        f32x2 sn = Emu2 * e2 * rc2[p];
        f32x2 arg = sn - e2 * PZ2[p];
        PZ2[p] *= (f32x2){__expf(arg[0]), __expf(arg[1])};
        S2[p] = sn;
      }
    }
  }
}

extern "C" void kernel_launch(void* const* d_in, const int* in_sizes, int n_in,
                              void* d_out, int out_size, void* d_ws, size_t ws_size,
                              hipStream_t stream){
  const float* x    = (const float*)d_in[0];
  const int*   batch= (const int*)  d_in[1];
  const float* W1   = (const float*)d_in[2];
  const float* W2   = (const float*)d_in[3];
  const float* a1r  = (const float*)d_in[4];
  const float* a2r  = (const float*)d_in[5];
  const float* a3r  = (const float*)d_in[6];
  float* out = (float*)d_out;

  const int T  = in_sizes[1];        // rows of x
  const int Bn = out_size / 128;     // segments

  short* wpack  = (short*)d_ws;                       // 32768 bf16
  int*   starts = (int*)(wpack + 32768);              // Bn+1 ints
  int*   cnt    = starts + (Bn + 2);                  // 2 ints
  int*   bigs   = cnt + 2;                            // Bn ints
  int*   smalls = bigs + Bn;                          // Bn ints

  k_pack<<<16, 256, 0, stream>>>(W1, wpack, cnt);
  k_seg<<<(Bn + 256) / 256, 256, 0, stream>>>(batch, starts, T, Bn, cnt, bigs, smalls);
  k_uot<<<Bn, 1024, 0, stream>>>(x, starts, cnt, bigs, smalls, wpack, W2,
                                 a1r, a2r, a3r, out, T);
}

// Round 13
// 81.857 us; speedup vs baseline: 2.7323x; 1.1260x over previous
//
#include <hip/hip_runtime.h>
#include <math.h>

#define NEGC -1000000000.0f

using f32x2 = __attribute__((ext_vector_type(2))) float;
using f32x4 = __attribute__((ext_vector_type(4))) float;
using s16x8 = __attribute__((ext_vector_type(8))) short;

__device__ __forceinline__ float softplusf(float v){ return log1pf(expf(v)); }
__device__ __forceinline__ short f2bf(float f){   // RNE f32->bf16
  unsigned u = __float_as_uint(f);
  unsigned r = (u + 0x7fffu + ((u >> 16) & 1u)) >> 16;
  return (short)r;
}
__device__ __forceinline__ float frcp(float v){ return __builtin_amdgcn_rcpf(v); }

// ---- cross-lane adds OFF the DS pipe (VALU permlane/DPP) ----
// permlane32_swap(v,v): r[0]={v_lo,v_lo} (round-9 evidence), r[1]={v_hi,v_hi}.
__device__ __forceinline__ float addx32(float v){   // valid lanes 0-31
#if __has_builtin(__builtin_amdgcn_permlane32_swap)
  auto r = __builtin_amdgcn_permlane32_swap(__float_as_uint(v), __float_as_uint(v), false, false);
  return v + __uint_as_float(r[1]);
#else
  return v + __shfl_xor(v, 32, 64);
#endif
}
__device__ __forceinline__ float addx16(float v){   // valid lanes 0-15 (input valid 0-31)
#if __has_builtin(__builtin_amdgcn_permlane16_swap)
  auto r = __builtin_amdgcn_permlane16_swap(__float_as_uint(v), __float_as_uint(v), false, false);
  return v + __uint_as_float(r[1]);
#else
  return v + __shfl_xor(v, 16, 64);
#endif
}
__device__ __forceinline__ float addx8(float v){    // xor8 via DPP row_ror:8 (within 16-row)
  int s = __builtin_amdgcn_update_dpp(0, __float_as_int(v), 0x128, 0xF, 0xF, true);
  return v + __int_as_float(s);
}
__device__ __forceinline__ float addq1(float v){    // xor1 via quad_perm [1,0,3,2]
  int s = __builtin_amdgcn_update_dpp(0, __float_as_int(v), 0xB1, 0xF, 0xF, true);
  return v + __int_as_float(s);
}
__device__ __forceinline__ float addq2(float v){    // xor2 via quad_perm [2,3,0,1]
  int s = __builtin_amdgcn_update_dpp(0, __float_as_int(v), 0x4E, 0xF, 0xF, true);
  return v + __int_as_float(s);
}

// ---------------- Kernel A: fused W1-pack + segment classification ----------------
__global__ __launch_bounds__(256) void k_prep(const float* __restrict__ W1,
                                              short* __restrict__ wpack,
                                              const int* __restrict__ batch,
                                              int* __restrict__ starts, int T, int Bn,
                                              int* __restrict__ cnt,
                                              int* __restrict__ bigs,
                                              int* __restrict__ smalls){
  const int bx  = blockIdx.x;
  const int tid = threadIdx.x;
  if (bx < 16){
    int gid  = bx * 256 + tid;                 // 0..4095
    int lane = gid & 63;
    int ft   = gid >> 6;                       // 0..63 = kt*4+dt
    int kt   = ft >> 2;
    int dt   = ft & 3;
    const float* src = W1 + (size_t)(kt * 16 + (lane & 15)) * 128 + dt * 32 + (lane >> 4) * 8;
    short o[8];
#pragma unroll
    for (int e = 0; e < 8; ++e) o[e] = f2bf(src[e]);
    *(s16x8*)(wpack + (size_t)gid * 8) = *(const s16x8*)o;
  } else {
    int t = (bx - 16) * 256 + tid;
    if (t > Bn) return;
    int lo = 0, hi = T;
    while (lo < hi){ int mid = (lo + hi) >> 1; if (batch[mid] < t) lo = mid + 1; else hi = mid; }
    if (t == Bn){ starts[Bn] = T; return; }
    starts[t] = lo;
    int lo2 = lo, hi2 = T;
    while (lo2 < hi2){ int mid = (lo2 + hi2) >> 1; if (batch[mid] <= t) lo2 = mid + 1; else hi2 = mid; }
    int nb = lo2 - lo;
    if (nb > 64) bigs[atomicAdd(&cnt[0], 1)] = t;
    else         smalls[atomicAdd(&cnt[1], 1)] = t;
  }
}

// ---------------- Kernel B: fused scores-MFMA + segment softmax + UOT-badmm ----------------
__global__ __launch_bounds__(1024)
void k_uot(const float* __restrict__ x,
           const int*   __restrict__ starts,
           const int*   __restrict__ cnt,
           const int*   __restrict__ bigs,
           const int*   __restrict__ smalls,
           const short* __restrict__ wpack,
           const float* __restrict__ W2,
           const float* __restrict__ a1r,
           const float* __restrict__ a2r,
           const float* __restrict__ a3r,
           float* __restrict__ out, int T){
  __shared__ __align__(16) short xs[2 * 64 * 128];      // 32 KB
  __shared__ __align__(16) float pbuf[16][164];
  __shared__ float scpart[2][4][64];
  __shared__ float rcsb[2][128];
  __shared__ float lq0s[2][128];
  __shared__ float sred[2][2];

  const int b   = blockIdx.x;
  const int tid = threadIdx.x;
  const int nbig   = cnt[0];
  const int nsmall = cnt[1];

  bool solo; int seg;
  const int half  = tid >> 9;          // 0/1
  const int tid_l = tid & 511;
  if (b < nbig){
    solo = true; seg = bigs[b];
  } else {
    const int i = (b - nbig) * 2 + half;
    solo = false;
    if ((b - nbig) * 2 >= nsmall) return;          // ghost block
    if (i >= nsmall) return;                       // half B missing -> waves exit
    seg = smalls[i];
  }

  const int start = starts[seg];
  const int nb    = starts[seg + 1] - start;
  const int hh    = solo ? 0 : half;
  const int tl    = solo ? tid : tid_l;
  const int PL    = solo ? 8 : 4;

  if (nb <= 0){
    if (tl < 128) out[(size_t)seg * 128 + tl] = 0.f;
    return;
  }

  const int n    = tl >> 3;
  const int j    = tl & 7;
  const int wvi  = tid >> 6;
  const int lane = tid & 63;
  const int part = tl & (PL - 1);
  const int col  = tl / PL;
  const int cidx = (col >> 4) * 20 + (col & 15);
  const int wq0  = solo ? 0 : half * 8;
  const int NWh  = solo ? 16 : 8;

  // ===== Phase 1: stage unit rows as swizzled bf16 =====
  const int u      = tid >> 9;
  const int utid   = tid & 511;
  const int ustart = solo ? (start + u * 64) : start;
#pragma unroll
  for (int itr = 0; itr < 2; ++itr){
    int L  = (itr * 512 + utid) * 8;
    int rr = L >> 7;
    int dc = L & 127;
    int grow = ustart + rr; grow = (grow < T) ? grow : (T - 1);
    const float4 v0 = *(const float4*)(x + (size_t)grow * 128 + dc);
    const float4 v1 = *(const float4*)(x + (size_t)grow * 128 + dc + 4);
    short o[8] = {f2bf(v0.x), f2bf(v0.y), f2bf(v0.z), f2bf(v0.w),
                  f2bf(v1.x), f2bf(v1.y), f2bf(v1.z), f2bf(v1.w)};
    int byte = u * 16384 + rr * 256 + ((dc * 2) ^ ((rr & 7) << 4));
    *(s16x8*)((char*)xs + byte) = *(const s16x8*)o;
  }
  __syncthreads();

  // ===== Phase 2: scores MFMA =====
  {
    const int lw = wvi & 7;
    const int wm = lw & 1;
    const int wn = lw >> 1;
    f32x4 acc[2][4];
#pragma unroll
    for (int mt = 0; mt < 2; ++mt)
#pragma unroll
      for (int kt = 0; kt < 4; ++kt) acc[mt][kt] = (f32x4){0.f, 0.f, 0.f, 0.f};

    const s16x8* wp = (const s16x8*)wpack;
#pragma unroll
    for (int dt = 0; dt < 4; ++dt){
      s16x8 av[2];
#pragma unroll
      for (int mt = 0; mt < 2; ++mt){
        int arow = wm * 32 + mt * 16 + (lane & 15);
        int byte = u * 16384 + arow * 256 + ((dt * 64 + (lane >> 4) * 16) ^ ((arow & 7) << 4));
        av[mt] = *(const s16x8*)((const char*)xs + byte);
      }
#pragma unroll
      for (int kt = 0; kt < 4; ++kt){
        s16x8 wv = wp[(size_t)((((wn * 4 + kt) * 4 + dt)) << 6) + lane];
#pragma unroll
        for (int mt = 0; mt < 2; ++mt)
          acc[mt][kt] = __builtin_amdgcn_mfma_f32_16x16x32_bf16(av[mt], wv, acc[mt][kt], 0, 0, 0);
      }
    }

    float psum[2][4] = {{0.f,0.f,0.f,0.f},{0.f,0.f,0.f,0.f}};
#pragma unroll
    for (int kt = 0; kt < 4; ++kt){
      const float w2v = W2[(wn * 4 + kt) * 16 + (lane & 15)];
#pragma unroll
      for (int mt = 0; mt < 2; ++mt)
#pragma unroll
        for (int r = 0; r < 4; ++r){
          float e = __expf(2.f * acc[mt][kt][r]);
          psum[mt][r] = fmaf((e - 1.f) * frcp(e + 1.f), w2v, psum[mt][r]);
        }
    }
#pragma unroll
    for (int mt = 0; mt < 2; ++mt)
#pragma unroll
      for (int r = 0; r < 4; ++r){
        float v = psum[mt][r];
        v = addq1(v); v = addq2(v);
        v += __shfl_xor(v, 4, 64); v += __shfl_xor(v, 8, 64);
        if ((lane & 15) == 0)
          scpart[u][wn][wm * 32 + mt * 16 + (lane >> 4) * 4 + r] = v;
      }
  }
  __syncthreads();

  // ===== Phase 3: raw masked scores into lq0s =====
  if (tl < 128){
    float sc = NEGC;
    if (tl < nb){
      const int ru = solo ? (tl >> 6) : hh;
      const int rl = tl & 63;
      sc = scpart[ru][0][rl] + scpart[ru][1][rl] + scpart[ru][2][rl] + scpart[ru][3][rl];
    }
    lq0s[hh][tl] = sc;
  }
  __syncthreads();

  // ===== Phase 4: per-half softmax stats; normalize at use (one barrier saved) =====
  if ((wvi & 7) == 0 && (!solo || wvi == 0)){
    float v0 = lq0s[hh][lane], v1 = lq0s[hh][lane + 64];
    float m = fmaxf(v0, v1);
#pragma unroll
    for (int msk = 32; msk; msk >>= 1) m = fmaxf(m, __shfl_xor(m, msk, 64));
    float s = __expf(v0 - m) + __expf(v1 - m);
#pragma unroll
    for (int msk = 32; msk; msk >>= 1) s += __shfl_xor(s, msk, 64);
    if (lane == 0){ sred[hh][0] = m; sred[hh][1] = s; }
  }
  __syncthreads();
  const float smax = sred[hh][0];
  const float rden = frcp(sred[hh][1] + 1e-16f);
  const bool  valid = (n < nb);
  const float lq0 = valid ? __logf(__expf(lq0s[hh][n] - smax) * rden + 1e-8f) : NEGC;

  // ===== Phase 5: UOT-badmm =====
  const float a1 = softplusf(a1r[0]);
  const float a2 = softplusf(a2r[0]);
  const float a3 = softplusf(a3r[0]);
  const float inv_a1 = 1.f / a1;
  const float log_p0 = logf(1.0f / 128.0f + 1e-8f);

  float emu_use[3];
  {
    float z1 = 0.f, lp = log_p0;
    emu_use[0] = __expf(log_p0);
#pragma unroll
    for (int i = 1; i < 3; ++i){
      float nm = (a1 * lp + a2 * log_p0 - z1) / (a1 + a2);
      z1 += a1 * (__expf(nm) - __expf(lp));
      emu_use[i] = __expf(nm); lp = nm;
    }
  }
  float eeta_use[4];
  {
    float z2 = 0.f, lp = lq0;
    eeta_use[0] = __expf(lq0);
#pragma unroll
    for (int i = 1; i < 4; ++i){
      float nm = (a1 * lp + a3 * lq0 - z2) / (a1 + a3);
      z2 += a1 * (__expf(nm) - __expf(lp));
      eeta_use[i] = __expf(nm); lp = nm;
    }
  }

  const int  nc    = valid ? n : (nb - 1);
  const float* xp  = x + (size_t)(start + nc) * 128 + j * 16;   // always in-bounds
  f32x2 EX2[8], PZ2[8], S2[8];
  {
    const float s0 = __expf(lq0 + log_p0);     // exactly 0 for invalid rows
#pragma unroll
    for (int p = 0; p < 8; p += 2){
      float4 v = *(const float4*)(xp + p * 2);
      EX2[p]   = (f32x2){__expf(v.x * inv_a1), __expf(v.y * inv_a1)};
      EX2[p+1] = (f32x2){__expf(v.z * inv_a1), __expf(v.w * inv_a1)};
    }
#pragma unroll
    for (int p = 0; p < 8; ++p){ PZ2[p] = (f32x2){1.f, 1.f}; S2[p] = (f32x2){s0, s0}; }
  }

#pragma unroll
  for (int it = 0; it < 4; ++it){
    f32x2 ES2[8];
    f32x2 rs2 = (f32x2){0.f, 0.f};
#pragma unroll
    for (int p = 0; p < 8; ++p){
      ES2[p] = EX2[p] * S2[p];
      rs2 += ES2[p] * PZ2[p];
    }
    float rsum = rs2[0] + rs2[1];
    rsum = addq1(rsum);
    rsum = addq2(rsum);
    rsum += __shfl_xor(rsum, 4, 64);
    const float Et = valid ? (eeta_use[it] * frcp(rsum)) : 0.f;
    const f32x2 Et2 = (f32x2){Et, Et};

    if (it == 3){
      float c[16];
#pragma unroll
      for (int p = 0; p < 8; p += 2){
        float4 v = *(const float4*)(xp + p * 2);
        f32x2 t0 = ES2[p]   * PZ2[p]   * Et2;
        f32x2 t1 = ES2[p+1] * PZ2[p+1] * Et2;
        c[p*2+0] = v.x * t0[0]; c[p*2+1] = v.y * t0[1];
        c[p*2+2] = v.z * t1[0]; c[p*2+3] = v.w * t1[1];
      }
#pragma unroll
      for (int k = 0; k < 16; ++k)
        c[k] = addx8(addx16(addx32(c[k])));          // valid lanes 0-7
      if (lane < 8){
        float* p = &pbuf[wvi][lane * 20];
        *(float4*)(p + 0)  = make_float4(c[0],  c[1],  c[2],  c[3]);
        *(float4*)(p + 4)  = make_float4(c[4],  c[5],  c[6],  c[7]);
        *(float4*)(p + 8)  = make_float4(c[8],  c[9],  c[10], c[11]);
        *(float4*)(p + 12) = make_float4(c[12], c[13], c[14], c[15]);
      }
      __syncthreads();
      {
        float s = 0.f;
        for (int wq = wq0 + part; wq < wq0 + NWh; wq += PL) s += pbuf[wq][cidx];
        s = addq2(addq1(s));
        if (PL == 8) s += __shfl_xor(s, 4, 64);
        if (part == 0) out[(size_t)seg * 128 + col] = 128.f * s;
      }
    } else {
      const float emu = emu_use[it];
      float c[16];
#pragma unroll
      for (int p = 0; p < 8; ++p){
        f32x2 e2 = ES2[p] * Et2;
        c[p*2+0] = e2[0]; c[p*2+1] = e2[1];
      }
#pragma unroll
      for (int k = 0; k < 16; ++k)
        c[k] = addx8(addx16(addx32(c[k])));          // valid lanes 0-7
      if (lane < 8){
        float* p = &pbuf[wvi][lane * 20];
        *(float4*)(p + 0)  = make_float4(c[0],  c[1],  c[2],  c[3]);
        *(float4*)(p + 4)  = make_float4(c[4],  c[5],  c[6],  c[7]);
        *(float4*)(p + 8)  = make_float4(c[8],  c[9],  c[10], c[11]);
        *(float4*)(p + 12) = make_float4(c[12], c[13], c[14], c[15]);
      }
      __syncthreads();                               // B1
      {
        float s = 0.f;
        for (int wq = wq0 + part; wq < wq0 + NWh; wq += PL) s += pbuf[wq][cidx];
        s = addq2(addq1(s));
        if (PL == 8) s += __shfl_xor(s, 4, 64);
        if (part == 0) rcsb[hh][col] = emu * frcp(fmaxf(s, 1e-30f));   // Emu folded in
      }
      __syncthreads();                               // B2
      f32x2 rc2[8];
      {
        const float4 r0 = *(const float4*)&rcsb[hh][j * 16 + 0];
        const float4 r1 = *(const float4*)&rcsb[hh][j * 16 + 4];
        const float4 r2 = *(const float4*)&rcsb[hh][j * 16 + 8];
        const float4 r3 = *(const float4*)&rcsb[hh][j * 16 + 12];
        rc2[0] = (f32x2){r0.x, r0.y}; rc2[1] = (f32x2){r0.z, r0.w};
        rc2[2] = (f32x2){r1.x, r1.y}; rc2[3] = (f32x2){r1.z, r1.w};
        rc2[4] = (f32x2){r2.x, r2.y}; rc2[5] = (f32x2){r2.z, r2.w};
        rc2[6] = (f32x2){r3.x, r3.y}; rc2[7] = (f32x2){r3.z, r3.w};
      }
#pragma unroll
      for (int p = 0; p < 8; ++p){
        f32x2 e2  = ES2[p] * Et2;
        f32x2 sn  = e2 * rc2[p];                     // exp(log_s_new)
        f32x2 arg = e2 * (rc2[p] - PZ2[p]);          // sn - e2*PZ
        PZ2[p] *= (f32x2){__expf(arg[0]), __expf(arg[1])};
        S2[p] = sn;
      }
    }
  }
}

extern "C" void kernel_launch(void* const* d_in, const int* in_sizes, int n_in,
                              void* d_out, int out_size, void* d_ws, size_t ws_size,
                              hipStream_t stream){
  const float* x    = (const float*)d_in[0];
  const int*   batch= (const int*)  d_in[1];
  const float* W1   = (const float*)d_in[2];
  const float* W2   = (const float*)d_in[3];
  const float* a1r  = (const float*)d_in[4];
  const float* a2r  = (const float*)d_in[5];
  const float* a3r  = (const float*)d_in[6];
  float* out = (float*)d_out;

  const int T  = in_sizes[1];        // rows of x
  const int Bn = out_size / 128;     // segments

  short* wpack  = (short*)d_ws;                       // 32768 bf16
  int*   starts = (int*)(wpack + 32768);              // Bn+1 ints
  int*   cnt    = starts + (Bn + 2);                  // 2 ints
  int*   bigs   = cnt + 2;                            // Bn ints
  int*   smalls = bigs + Bn;                          // Bn ints

  hipMemsetAsync(cnt, 0, 2 * sizeof(int), stream);
  const int segBlocks = (Bn + 256) / 256;
  k_prep<<<16 + segBlocks, 256, 0, stream>>>(W1, wpack, batch, starts, T, Bn,
                                             cnt, bigs, smalls);
  k_uot<<<Bn, 1024, 0, stream>>>(x, starts, cnt, bigs, smalls, wpack, W2,
                                 a1r, a2r, a3r, out, T);
}